// Round 1
// baseline (2442.617 us; speedup 1.0000x reference)
//
#include <hip/hip_runtime.h>
#include <stdint.h>

// ---------------------------------------------------------------------------
// Q_Attention: quantized ViT attention block, bit-faithful to the JAX/numpy ref.
// B=32, N=512, C=768, H=12, hd=64.  All quantized tensors are small ints, so
// fp32 FMA accumulation is exact.  Sensitive fp ops use __f*_rn to pin IEEE
// fp32 semantics (no contraction); reductions replicate numpy pairwise order.
// ---------------------------------------------------------------------------

#define BB 32
#define NN 512
#define CC 768
#define HH 12
#define HD 64
#define M_ROWS (BB * NN)     // 16384
#define QKV_C (3 * CC)       // 2304

__device__ __forceinline__ float fadd(float a, float b) { return __fadd_rn(a, b); }
__device__ __forceinline__ float fmul(float a, float b) { return __fmul_rn(a, b); }
__device__ __forceinline__ float fdiv(float a, float b) { return __fdiv_rn(a, b); }
__device__ __forceinline__ float fsub(float a, float b) { return __fsub_rn(a, b); }

// numpy pairwise_sum, n=96 (no remainder): 8 accumulators, then pairwise combine
__device__ float np_sum_96(const float* a) {
  float r[8];
#pragma unroll
  for (int j = 0; j < 8; j++) r[j] = a[j];
  for (int i = 8; i < 96; i += 8)
#pragma unroll
    for (int j = 0; j < 8; j++) r[j] = fadd(r[j], a[i + j]);
  return fadd(fadd(fadd(r[0], r[1]), fadd(r[2], r[3])),
              fadd(fadd(r[4], r[5]), fadd(r[6], r[7])));
}

// numpy pairwise mean of 768: 768->384->192->96 tree
__device__ float np_mean_768(const float* a) {
  float s0 = fadd(fadd(np_sum_96(a), np_sum_96(a + 96)),
                  fadd(np_sum_96(a + 192), np_sum_96(a + 288)));
  float s1 = fadd(fadd(np_sum_96(a + 384), np_sum_96(a + 480)),
                  fadd(np_sum_96(a + 576), np_sum_96(a + 672)));
  return fdiv(fadd(s0, s1), 768.0f);
}

// numpy pairwise mean of 12: 8-acc combine + 4 sequential remainder adds
__device__ float np_mean_12(const float* a) {
  float r[8];
#pragma unroll
  for (int j = 0; j < 8; j++) r[j] = a[j];
  float res = fadd(fadd(fadd(r[0], r[1]), fadd(r[2], r[3])),
                   fadd(fadd(r[4], r[5]), fadd(r[6], r[7])));
  res = fadd(res, a[8]);
  res = fadd(res, a[9]);
  res = fadd(res, a[10]);
  res = fadd(res, a[11]);
  return fdiv(res, 12.0f);
}

// numpy-order mean + (std(ddof=1)+1e-5) over 64 contiguous values
__device__ void np_stats_64(const float* x, float* mean_out, float* den_out) {
  float r[8];
#pragma unroll
  for (int j = 0; j < 8; j++) r[j] = x[j];
  for (int i = 8; i < 64; i += 8)
#pragma unroll
    for (int j = 0; j < 8; j++) r[j] = fadd(r[j], x[i + j]);
  float s = fadd(fadd(fadd(r[0], r[1]), fadd(r[2], r[3])),
                 fadd(fadd(r[4], r[5]), fadd(r[6], r[7])));
  float mean = fdiv(s, 64.0f);
#pragma unroll
  for (int j = 0; j < 8; j++) {
    float d = fsub(x[j], mean);
    r[j] = fmul(d, d);
  }
  for (int i = 8; i < 64; i += 8)
#pragma unroll
    for (int j = 0; j < 8; j++) {
      float d = fsub(x[i + j], mean);
      r[j] = fadd(r[j], fmul(d, d));
    }
  float ss = fadd(fadd(fadd(r[0], r[1]), fadd(r[2], r[3])),
                  fadd(fadd(r[4], r[5]), fadd(r[6], r[7])));
  float var = fdiv(ss, 63.0f);
  float sd = __fsqrt_rn(var);
  *mean_out = mean;
  *den_out = fadd(sd, 1e-5f);
}

__device__ __forceinline__ void unpack16(int4 v, float* dst) {
  int w[4] = {v.x, v.y, v.z, v.w};
#pragma unroll
  for (int q = 0; q < 4; q++)
#pragma unroll
    for (int b = 0; b < 4; b++)
      dst[q * 4 + b] = (float)((int8_t)((w[q] >> (8 * b)) & 0xff));
}

// ---------------------------------------------------------------------------
// prep: scalar means + folded LN quant params + integer qkv bias
// scal: [0]=a_in [1]=qact_m [2]=kact_m [3]=vact_m [4]=attnact_m [5]=pact_m
// qparams: [0:64]=qalpha [64:128]=qbias [128:192]=kalpha [192:256]=kbias
// ---------------------------------------------------------------------------
__global__ void prep_kernel(const float* __restrict__ qkv_act_alpha,
                            const float* __restrict__ proj_act_alpha,
                            const float* __restrict__ qact_alpha,
                            const float* __restrict__ kact_alpha,
                            const float* __restrict__ vact_alpha,
                            const float* __restrict__ attnact_alpha,
                            const float* __restrict__ normq_w,
                            const float* __restrict__ normq_b,
                            const float* __restrict__ normk_w,
                            const float* __restrict__ normk_b,
                            const float* __restrict__ qkv_bias,
                            const float* __restrict__ qkv_alpha,
                            float* __restrict__ scal,
                            float* __restrict__ qparams,
                            float* __restrict__ biasq) {
  __shared__ float s_scal[8];
  int tid = threadIdx.x;
  if (tid == 0) s_scal[0] = np_mean_768(qkv_act_alpha);
  if (tid == 1) s_scal[5] = np_mean_768(proj_act_alpha);
  if (tid == 2) s_scal[1] = np_mean_12(qact_alpha);
  if (tid == 3) s_scal[2] = np_mean_12(kact_alpha);
  if (tid == 4) s_scal[3] = np_mean_12(vact_alpha);
  if (tid == 5) s_scal[4] = np_mean_12(attnact_alpha);
  __syncthreads();
  if (tid < 6) scal[tid] = s_scal[tid];
  if (tid < 64) {
    qparams[tid]       = fdiv(s_scal[1], normq_w[tid]);   // act_a / nw
    qparams[64 + tid]  = fdiv(normq_b[tid], normq_w[tid]); // nb / nw
    qparams[128 + tid] = fdiv(s_scal[2], normk_w[tid]);
    qparams[192 + tid] = fdiv(normk_b[tid], normk_w[tid]);
  }
  float a_in = s_scal[0];
  for (int c = tid; c < QKV_C; c += blockDim.x)
    biasq[c] = truncf(fdiv(fdiv(qkv_bias[c], a_in), qkv_alpha[c]));
}

// x0_q = round(clip(x0 / a_in, -8, 7)) -> int8
__global__ void quant_x0_kernel(const float* __restrict__ x0,
                                const float* __restrict__ scal,
                                int8_t* __restrict__ x0q, int total4) {
  int i = blockIdx.x * blockDim.x + threadIdx.x;
  if (i >= total4) return;
  float a_in = scal[0];
  float4 v = ((const float4*)x0)[i];
  char4 o;
  o.x = (int8_t)rintf(fminf(fmaxf(fdiv(v.x, a_in), -8.f), 7.f));
  o.y = (int8_t)rintf(fminf(fmaxf(fdiv(v.y, a_in), -8.f), 7.f));
  o.z = (int8_t)rintf(fminf(fmaxf(fdiv(v.z, a_in), -8.f), 7.f));
  o.w = (int8_t)rintf(fminf(fmaxf(fdiv(v.w, a_in), -8.f), 7.f));
  ((char4*)x0q)[i] = o;
}

// row-wise 4-bit weight quant: wq = round(clip(w / alpha[row], -8, 7))
__global__ void quant_w_kernel(const float* __restrict__ w,
                               const float* __restrict__ alpha,
                               int8_t* __restrict__ wq, int total) {
  int i = blockIdx.x * blockDim.x + threadIdx.x;
  if (i >= total) return;
  int row = i / CC;
  float t = fminf(fmaxf(fdiv(w[i], alpha[row]), -8.f), 7.f);
  wq[i] = (int8_t)rintf(t);
}

// ---------------------------------------------------------------------------
// GEMM1: qkv = x0q @ wq^T + biasq, with fused epilogue:
//   q/k: per-row scaled LayerNorm + 3b quant -> q2/k2 int8 [B,H,N,hd]
//   v:   3b quant -> v2 int8 [B,H,N,hd]
// tile 64x64, block 256 threads, 4x4 micro-tile / thread.
// ---------------------------------------------------------------------------
__global__ __launch_bounds__(256) void gemm_qkv_kernel(
    const int8_t* __restrict__ Aq, const int8_t* __restrict__ Wq,
    const float* __restrict__ biasq, const float* __restrict__ scal,
    const float* __restrict__ qkv_alpha, const float* __restrict__ qparams,
    int8_t* __restrict__ q2, int8_t* __restrict__ k2, int8_t* __restrict__ v2) {
  __shared__ float As[64][65];
  __shared__ float Bs[64][65];
  __shared__ float meanS[64], denS[64];
  const int g = blockIdx.x, rb = blockIdx.y;
  const int tid = threadIdx.x, tx = tid & 15, ty = tid >> 4;
  const int row0 = rb * 64, col0 = g * 64;
  const int lr = tid >> 2, loff = (tid & 3) << 4;
  float acc[4][4] = {};
  for (int k0 = 0; k0 < CC; k0 += 64) {
    int4 av = *(const int4*)(Aq + (size_t)(row0 + lr) * CC + k0 + loff);
    int4 bv = *(const int4*)(Wq + (size_t)(col0 + lr) * CC + k0 + loff);
    unpack16(av, &As[lr][loff]);
    unpack16(bv, &Bs[lr][loff]);
    __syncthreads();
#pragma unroll 8
    for (int k = 0; k < 64; k++) {
      float a[4], b[4];
#pragma unroll
      for (int i = 0; i < 4; i++) a[i] = As[ty * 4 + i][k];
#pragma unroll
      for (int j = 0; j < 4; j++) b[j] = Bs[tx * 4 + j][k];
#pragma unroll
      for (int i = 0; i < 4; i++)
#pragma unroll
        for (int j = 0; j < 4; j++) acc[i][j] += a[i] * b[j];
    }
    __syncthreads();
  }

  const int which = g / HH, h = g % HH;
  const int b_idx = row0 >> 9, nbase = row0 & (NN - 1);
  const float a_in = scal[0];

  if (which == 2) {  // v path: elementwise 3b quant
    const float vact = scal[3];
#pragma unroll
    for (int i = 0; i < 4; i++)
#pragma unroll
      for (int j = 0; j < 4; j++) {
        int col = col0 + tx * 4 + j;
        float vint = fadd(acc[i][j], biasq[col]);  // exact int
        float va = fdiv(vact, fmul(a_in, qkv_alpha[col]));
        float t = fminf(fmaxf(fdiv(vint, va), -4.f), 3.f);
        int n = nbase + ty * 4 + i;
        v2[(((size_t)b_idx * HH + h) * NN + n) * HD + (tx * 4 + j)] =
            (int8_t)rintf(t);
      }
  } else {  // q/k path: scaled LN + 3b quant
    float (*XS)[65] = As;  // reuse A-tile LDS for xs
    float xs_loc[4][4];
#pragma unroll
    for (int i = 0; i < 4; i++)
#pragma unroll
      for (int j = 0; j < 4; j++) {
        int col = col0 + tx * 4 + j;
        float vint = fadd(acc[i][j], biasq[col]);
        float x = fmul(vint, qkv_alpha[col]);
        xs_loc[i][j] = x;
        XS[ty * 4 + i][tx * 4 + j] = x;
      }
    __syncthreads();
    if (tid < 64) np_stats_64(&XS[tid][0], &meanS[tid], &denS[tid]);
    __syncthreads();
    const float* ap = qparams + (which == 0 ? 0 : 128);
    int8_t* dst = (which == 0) ? q2 : k2;
#pragma unroll
    for (int i = 0; i < 4; i++)
#pragma unroll
      for (int j = 0; j < 4; j++) {
        int d = tx * 4 + j, r = ty * 4 + i;
        float xn = fdiv(fsub(xs_loc[i][j], meanS[r]), denS[r]);
        float t = fdiv(fadd(xn, ap[64 + d]), ap[d]);
        t = fminf(fmaxf(t, -4.f), 3.f);
        int n = nbase + r;
        dst[(((size_t)b_idx * HH + h) * NN + n) * HD + d] = (int8_t)rintf(t);
      }
  }
}

// ---------------------------------------------------------------------------
// Attention: per (b,h,qtile64), 2-pass flash-style.
// Pass A: row sums of 2^m in numpy pairwise order (8-acc per 128 = 2 k-tiles).
// Pass B: attn = round(clip((p/S)/attnact, 0, 7)); x1 += attn @ v2; quant.
// ---------------------------------------------------------------------------
__global__ __launch_bounds__(256) void attn_kernel(
    const int8_t* __restrict__ q2, const int8_t* __restrict__ k2,
    const int8_t* __restrict__ v2, const float* __restrict__ scal,
    int8_t* __restrict__ x1q) {
  __shared__ float Qs[64][65], Ks[64][65], Vs[64][65];
  __shared__ float Srow[64];
  const int qt = blockIdx.x, bh = blockIdx.y;
  const int b_idx = bh / HH, h = bh % HH;
  const int tid = threadIdx.x, tx = tid & 15, ty = tid >> 4;
  const float qact = scal[1], kact = scal[2], vact = scal[3];
  const float attnm = scal[4], pact = scal[5];
  const float sm = fmul(fmul(0.125f, qact), kact);         // scale*qm*km
  const float coef = fmul(1.4426950408889634f, sm);        // (1/ln2 as f32)*sm
  const float pa = fdiv(pact, fmul(attnm, vact));
  const size_t base = (size_t)bh * NN * HD;
  const int lr = tid >> 2, loff = (tid & 3) << 4;
  {
    int4 qv = *(const int4*)(q2 + base + (size_t)(qt * 64 + lr) * HD + loff);
    unpack16(qv, &Qs[lr][loff]);
  }
  float racc[8], Bacc[4];
  __syncthreads();

  // ---- pass A: row sums ----
  for (int kt = 0; kt < 8; kt++) {
    int4 kv = *(const int4*)(k2 + base + (size_t)(kt * 64 + lr) * HD + loff);
    unpack16(kv, &Ks[lr][loff]);
    __syncthreads();
    float sc[4][4] = {};
#pragma unroll 8
    for (int d = 0; d < 64; d++) {
      float a[4], bb[4];
#pragma unroll
      for (int i = 0; i < 4; i++) a[i] = Qs[ty * 4 + i][d];
#pragma unroll
      for (int j = 0; j < 4; j++) bb[j] = Ks[tx * 4 + j][d];
#pragma unroll
      for (int i = 0; i < 4; i++)
#pragma unroll
        for (int j = 0; j < 4; j++) sc[i][j] += a[i] * bb[j];
    }
    __syncthreads();
#pragma unroll
    for (int i = 0; i < 4; i++)
#pragma unroll
      for (int j = 0; j < 4; j++) {
        float e = truncf(fmul(fmul(coef, sc[i][j]), 128.f));
        int m = (int)rintf(fmul(e, 0.0078125f));
        Ks[ty * 4 + i][tx * 4 + j] = ldexpf(1.0f, m);  // exact 2^m
      }
    __syncthreads();
    if (tid < 64) {
      if ((kt & 1) == 0) {
#pragma unroll
        for (int j = 0; j < 8; j++) racc[j] = Ks[tid][j];
        for (int i = 8; i < 64; i += 8)
#pragma unroll
          for (int j = 0; j < 8; j++) racc[j] = fadd(racc[j], Ks[tid][i + j]);
      } else {
        for (int i = 0; i < 64; i += 8)
#pragma unroll
          for (int j = 0; j < 8; j++) racc[j] = fadd(racc[j], Ks[tid][i + j]);
        Bacc[kt >> 1] =
            fadd(fadd(fadd(racc[0], racc[1]), fadd(racc[2], racc[3])),
                 fadd(fadd(racc[4], racc[5]), fadd(racc[6], racc[7])));
      }
    }
    __syncthreads();
  }
  if (tid < 64)
    Srow[tid] = fadd(fadd(Bacc[0], Bacc[1]), fadd(Bacc[2], Bacc[3]));
  __syncthreads();

  // ---- pass B: quantized attention @ V ----
  float xacc[4][4] = {};
  for (int kt = 0; kt < 8; kt++) {
    int4 kv = *(const int4*)(k2 + base + (size_t)(kt * 64 + lr) * HD + loff);
    unpack16(kv, &Ks[lr][loff]);
    int4 vv = *(const int4*)(v2 + base + (size_t)(kt * 64 + lr) * HD + loff);
    unpack16(vv, &Vs[lr][loff]);
    __syncthreads();
    float sc[4][4] = {};
#pragma unroll 8
    for (int d = 0; d < 64; d++) {
      float a[4], bb[4];
#pragma unroll
      for (int i = 0; i < 4; i++) a[i] = Qs[ty * 4 + i][d];
#pragma unroll
      for (int j = 0; j < 4; j++) bb[j] = Ks[tx * 4 + j][d];
#pragma unroll
      for (int i = 0; i < 4; i++)
#pragma unroll
        for (int j = 0; j < 4; j++) sc[i][j] += a[i] * bb[j];
    }
    __syncthreads();
#pragma unroll
    for (int i = 0; i < 4; i++)
#pragma unroll
      for (int j = 0; j < 4; j++) {
        float e = truncf(fmul(fmul(coef, sc[i][j]), 128.f));
        int m = (int)rintf(fmul(e, 0.0078125f));
        float p = ldexpf(1.0f, m);
        float t = fdiv(fdiv(p, Srow[ty * 4 + i]), attnm);
        t = fminf(fmaxf(t, 0.f), 7.f);
        Ks[ty * 4 + i][tx * 4 + j] = rintf(t);  // int attn weight
      }
    __syncthreads();
#pragma unroll 4
    for (int kk = 0; kk < 64; kk++) {
      float a[4], bb[4];
#pragma unroll
      for (int i = 0; i < 4; i++) a[i] = Ks[ty * 4 + i][kk];
#pragma unroll
      for (int j = 0; j < 4; j++) bb[j] = Vs[kk][tx * 4 + j];
#pragma unroll
      for (int i = 0; i < 4; i++)
#pragma unroll
        for (int j = 0; j < 4; j++) xacc[i][j] += a[i] * bb[j];
    }
    __syncthreads();
  }
  // epilogue: x1_q = round(clip(x1/pa, -4, 3)) -> [B,N,C] layout
#pragma unroll
  for (int i = 0; i < 4; i++)
#pragma unroll
    for (int j = 0; j < 4; j++) {
      int n = qt * 64 + ty * 4 + i, d = tx * 4 + j;
      float t = fminf(fmaxf(fdiv(xacc[i][j], pa), -4.f), 3.f);
      x1q[((size_t)(b_idx * NN + n)) * CC + h * HD + d] = (int8_t)rintf(t);
    }
}

// ---------------------------------------------------------------------------
// GEMM2: out = (x1q @ pwq^T) * proj_alpha * pact_m + proj_bias   (fp32 out)
// ---------------------------------------------------------------------------
__global__ __launch_bounds__(256) void gemm_proj_kernel(
    const int8_t* __restrict__ Aq, const int8_t* __restrict__ Wq,
    const float* __restrict__ proj_alpha, const float* __restrict__ proj_bias,
    const float* __restrict__ scal, float* __restrict__ out) {
  __shared__ float As[64][65];
  __shared__ float Bs[64][65];
  const int g = blockIdx.x, rb = blockIdx.y;
  const int tid = threadIdx.x, tx = tid & 15, ty = tid >> 4;
  const int row0 = rb * 64, col0 = g * 64;
  const int lr = tid >> 2, loff = (tid & 3) << 4;
  float acc[4][4] = {};
  for (int k0 = 0; k0 < CC; k0 += 64) {
    int4 av = *(const int4*)(Aq + (size_t)(row0 + lr) * CC + k0 + loff);
    int4 bv = *(const int4*)(Wq + (size_t)(col0 + lr) * CC + k0 + loff);
    unpack16(av, &As[lr][loff]);
    unpack16(bv, &Bs[lr][loff]);
    __syncthreads();
#pragma unroll 8
    for (int k = 0; k < 64; k++) {
      float a[4], b[4];
#pragma unroll
      for (int i = 0; i < 4; i++) a[i] = As[ty * 4 + i][k];
#pragma unroll
      for (int j = 0; j < 4; j++) b[j] = Bs[tx * 4 + j][k];
#pragma unroll
      for (int i = 0; i < 4; i++)
#pragma unroll
        for (int j = 0; j < 4; j++) acc[i][j] += a[i] * b[j];
    }
    __syncthreads();
  }
  const float pact = scal[5];
#pragma unroll
  for (int i = 0; i < 4; i++)
#pragma unroll
    for (int j = 0; j < 4; j++) {
      int col = col0 + tx * 4 + j;
      int m = row0 + ty * 4 + i;
      out[(size_t)m * CC + col] =
          fadd(fmul(fmul(acc[i][j], proj_alpha[col]), pact), proj_bias[col]);
    }
}

extern "C" void kernel_launch(void* const* d_in, const int* in_sizes, int n_in,
                              void* d_out, int out_size, void* d_ws,
                              size_t ws_size, hipStream_t stream) {
  const float* x0 = (const float*)d_in[0];
  const float* qkv_w = (const float*)d_in[1];
  const float* qkv_alpha = (const float*)d_in[2];
  const float* qkv_bias = (const float*)d_in[3];
  const float* qkv_act_alpha = (const float*)d_in[4];
  const float* proj_w = (const float*)d_in[5];
  const float* proj_alpha = (const float*)d_in[6];
  const float* proj_bias = (const float*)d_in[7];
  const float* proj_act_alpha = (const float*)d_in[8];
  const float* normq_w = (const float*)d_in[9];
  const float* normq_b = (const float*)d_in[10];
  const float* normk_w = (const float*)d_in[11];
  const float* normk_b = (const float*)d_in[12];
  const float* qact_alpha = (const float*)d_in[13];
  const float* kact_alpha = (const float*)d_in[14];
  const float* vact_alpha = (const float*)d_in[15];
  const float* attnact_alpha = (const float*)d_in[16];

  char* ws = (char*)d_ws;
  size_t off = 0;
  auto alloc = [&](size_t bytes) -> char* {
    char* p = ws + off;
    off += (bytes + 255) & ~(size_t)255;
    return p;
  };
  float* scal = (float*)alloc(64 * 4);
  float* qparams = (float*)alloc(256 * 4);
  float* biasq = (float*)alloc(QKV_C * 4);
  int8_t* x0q = (int8_t*)alloc((size_t)M_ROWS * CC);
  int8_t* wq = (int8_t*)alloc((size_t)QKV_C * CC);
  int8_t* pwq = (int8_t*)alloc((size_t)CC * CC);
  int8_t* q2 = (int8_t*)alloc((size_t)BB * HH * NN * HD);
  int8_t* k2 = (int8_t*)alloc((size_t)BB * HH * NN * HD);
  int8_t* v2 = (int8_t*)alloc((size_t)BB * HH * NN * HD);
  int8_t* x1q = (int8_t*)alloc((size_t)M_ROWS * CC);

  prep_kernel<<<1, 256, 0, stream>>>(qkv_act_alpha, proj_act_alpha, qact_alpha,
                                     kact_alpha, vact_alpha, attnact_alpha,
                                     normq_w, normq_b, normk_w, normk_b,
                                     qkv_bias, qkv_alpha, scal, qparams, biasq);

  int total4 = M_ROWS * CC / 4;
  quant_x0_kernel<<<(total4 + 255) / 256, 256, 0, stream>>>(x0, scal, x0q,
                                                            total4);
  quant_w_kernel<<<(QKV_C * CC + 255) / 256, 256, 0, stream>>>(
      qkv_w, qkv_alpha, wq, QKV_C * CC);
  quant_w_kernel<<<(CC * CC + 255) / 256, 256, 0, stream>>>(proj_w, proj_alpha,
                                                            pwq, CC * CC);

  gemm_qkv_kernel<<<dim3(QKV_C / 64, M_ROWS / 64), 256, 0, stream>>>(
      x0q, wq, biasq, scal, qkv_alpha, qparams, q2, k2, v2);

  attn_kernel<<<dim3(NN / 64, BB * HH), 256, 0, stream>>>(q2, k2, v2, scal,
                                                          x1q);

  gemm_proj_kernel<<<dim3(CC / 64, M_ROWS / 64), 256, 0, stream>>>(
      x1q, pwq, proj_alpha, proj_bias, scal, (float*)d_out);
}

// Round 2
// 454.255 us; speedup vs baseline: 5.3772x; 5.3772x over previous
//
#include <hip/hip_runtime.h>
#include <stdint.h>

// ---------------------------------------------------------------------------
// Q_Attention: quantized ViT attention block, bit-faithful to the JAX/numpy ref.
// B=32, N=512, C=768, H=12, hd=64.  All GEMMs on i8 MFMA (int32 acc, exact).
// Sensitive fp ops use __f*_rn to pin IEEE fp32 semantics; reductions either
// replicate numpy pairwise order or are provably order-independent (2^m sums).
// ---------------------------------------------------------------------------

#define BB 32
#define NN 512
#define CC 768
#define HH 12
#define HD 64
#define M_ROWS (BB * NN)     // 16384
#define QKV_C (3 * CC)       // 2304

typedef int v4i __attribute__((ext_vector_type(4)));

__device__ __forceinline__ float fadd(float a, float b) { return __fadd_rn(a, b); }
__device__ __forceinline__ float fmul(float a, float b) { return __fmul_rn(a, b); }
__device__ __forceinline__ float fdiv(float a, float b) { return __fdiv_rn(a, b); }
__device__ __forceinline__ float fsub(float a, float b) { return __fsub_rn(a, b); }

// numpy pairwise_sum, n=96 (no remainder): 8 accumulators, then pairwise combine
__device__ float np_sum_96(const float* a) {
  float r[8];
#pragma unroll
  for (int j = 0; j < 8; j++) r[j] = a[j];
  for (int i = 8; i < 96; i += 8)
#pragma unroll
    for (int j = 0; j < 8; j++) r[j] = fadd(r[j], a[i + j]);
  return fadd(fadd(fadd(r[0], r[1]), fadd(r[2], r[3])),
              fadd(fadd(r[4], r[5]), fadd(r[6], r[7])));
}

// numpy pairwise mean of 768: 768->384->192->96 tree
__device__ float np_mean_768(const float* a) {
  float s0 = fadd(fadd(np_sum_96(a), np_sum_96(a + 96)),
                  fadd(np_sum_96(a + 192), np_sum_96(a + 288)));
  float s1 = fadd(fadd(np_sum_96(a + 384), np_sum_96(a + 480)),
                  fadd(np_sum_96(a + 576), np_sum_96(a + 672)));
  return fdiv(fadd(s0, s1), 768.0f);
}

// numpy pairwise mean of 12: 8-acc combine + 4 sequential remainder adds
__device__ float np_mean_12(const float* a) {
  float r[8];
#pragma unroll
  for (int j = 0; j < 8; j++) r[j] = a[j];
  float res = fadd(fadd(fadd(r[0], r[1]), fadd(r[2], r[3])),
                   fadd(fadd(r[4], r[5]), fadd(r[6], r[7])));
  res = fadd(res, a[8]);
  res = fadd(res, a[9]);
  res = fadd(res, a[10]);
  res = fadd(res, a[11]);
  return fdiv(res, 12.0f);
}

// numpy-order mean + (std(ddof=1)+1e-5) over 64 contiguous values
__device__ void np_stats_64(const float* x, float* mean_out, float* den_out) {
  float r[8];
#pragma unroll
  for (int j = 0; j < 8; j++) r[j] = x[j];
  for (int i = 8; i < 64; i += 8)
#pragma unroll
    for (int j = 0; j < 8; j++) r[j] = fadd(r[j], x[i + j]);
  float s = fadd(fadd(fadd(r[0], r[1]), fadd(r[2], r[3])),
                 fadd(fadd(r[4], r[5]), fadd(r[6], r[7])));
  float mean = fdiv(s, 64.0f);
#pragma unroll
  for (int j = 0; j < 8; j++) {
    float d = fsub(x[j], mean);
    r[j] = fmul(d, d);
  }
  for (int i = 8; i < 64; i += 8)
#pragma unroll
    for (int j = 0; j < 8; j++) {
      float d = fsub(x[i + j], mean);
      r[j] = fadd(r[j], fmul(d, d));
    }
  float ss = fadd(fadd(fadd(r[0], r[1]), fadd(r[2], r[3])),
                  fadd(fadd(r[4], r[5]), fadd(r[6], r[7])));
  float var = fdiv(ss, 63.0f);
  float sd = __fsqrt_rn(var);
  *mean_out = mean;
  *den_out = fadd(sd, 1e-5f);
}

// ---------------------------------------------------------------------------
// prep: scalar means + folded LN quant params + integer qkv bias
// scal: [0]=a_in [1]=qact_m [2]=kact_m [3]=vact_m [4]=attnact_m [5]=pact_m
// qparams: [0:64]=qalpha [64:128]=qbias [128:192]=kalpha [192:256]=kbias
// ---------------------------------------------------------------------------
__global__ void prep_kernel(const float* __restrict__ qkv_act_alpha,
                            const float* __restrict__ proj_act_alpha,
                            const float* __restrict__ qact_alpha,
                            const float* __restrict__ kact_alpha,
                            const float* __restrict__ vact_alpha,
                            const float* __restrict__ attnact_alpha,
                            const float* __restrict__ normq_w,
                            const float* __restrict__ normq_b,
                            const float* __restrict__ normk_w,
                            const float* __restrict__ normk_b,
                            const float* __restrict__ qkv_bias,
                            const float* __restrict__ qkv_alpha,
                            float* __restrict__ scal,
                            float* __restrict__ qparams,
                            float* __restrict__ biasq) {
  __shared__ float s_scal[8];
  int tid = threadIdx.x;
  if (tid == 0) s_scal[0] = np_mean_768(qkv_act_alpha);
  if (tid == 1) s_scal[5] = np_mean_768(proj_act_alpha);
  if (tid == 2) s_scal[1] = np_mean_12(qact_alpha);
  if (tid == 3) s_scal[2] = np_mean_12(kact_alpha);
  if (tid == 4) s_scal[3] = np_mean_12(vact_alpha);
  if (tid == 5) s_scal[4] = np_mean_12(attnact_alpha);
  __syncthreads();
  if (tid < 6) scal[tid] = s_scal[tid];
  if (tid < 64) {
    qparams[tid]       = fdiv(s_scal[1], normq_w[tid]);    // act_a / nw
    qparams[64 + tid]  = fdiv(normq_b[tid], normq_w[tid]); // nb / nw
    qparams[128 + tid] = fdiv(s_scal[2], normk_w[tid]);
    qparams[192 + tid] = fdiv(normk_b[tid], normk_w[tid]);
  }
  float a_in = s_scal[0];
  for (int c = tid; c < QKV_C; c += blockDim.x)
    biasq[c] = truncf(fdiv(fdiv(qkv_bias[c], a_in), qkv_alpha[c]));
}

// x0_q = round(clip(x0 / a_in, -8, 7)) -> int8
__global__ void quant_x0_kernel(const float* __restrict__ x0,
                                const float* __restrict__ scal,
                                int8_t* __restrict__ x0q, int total4) {
  int i = blockIdx.x * blockDim.x + threadIdx.x;
  if (i >= total4) return;
  float a_in = scal[0];
  float4 v = ((const float4*)x0)[i];
  char4 o;
  o.x = (int8_t)rintf(fminf(fmaxf(fdiv(v.x, a_in), -8.f), 7.f));
  o.y = (int8_t)rintf(fminf(fmaxf(fdiv(v.y, a_in), -8.f), 7.f));
  o.z = (int8_t)rintf(fminf(fmaxf(fdiv(v.z, a_in), -8.f), 7.f));
  o.w = (int8_t)rintf(fminf(fmaxf(fdiv(v.w, a_in), -8.f), 7.f));
  ((char4*)x0q)[i] = o;
}

// row-wise 4-bit weight quant: wq = round(clip(w / alpha[row], -8, 7))
__global__ void quant_w_kernel(const float* __restrict__ w,
                               const float* __restrict__ alpha,
                               int8_t* __restrict__ wq, int total) {
  int i = blockIdx.x * blockDim.x + threadIdx.x;
  if (i >= total) return;
  int row = i / CC;
  float t = fminf(fmaxf(fdiv(w[i], alpha[row]), -8.f), 7.f);
  wq[i] = (int8_t)rintf(t);
}

// ---------------------------------------------------------------------------
// GEMM1 (i8 MFMA, transposed orientation D = W·X^T):
//   qkv-int = x0q @ wq^T + biasq, fused epilogues:
//   q/k: scaled LayerNorm + 3b quant -> q2/k2 int8 [B,H,N,hd]
//   v:   3b quant -> v2t int8 [B,H,hd,N]   (pre-transposed for AV staging)
// Block: 64 rows x 64 cols, 256 thr (4 waves); wave w owns rows [16w,16w+16).
// Lane frag: m = 16w + (lane&15); C reg r of subtile s -> col 16s+4*quad+r
// (4 consecutive out-channels -> dword-packed int8 transpose tiles).
// ---------------------------------------------------------------------------
__global__ __launch_bounds__(256) void gemm_qkv_kernel(
    const int8_t* __restrict__ Aq, const int8_t* __restrict__ Wq,
    const float* __restrict__ biasq, const float* __restrict__ scal,
    const float* __restrict__ qkv_alpha, const float* __restrict__ qparams,
    int8_t* __restrict__ q2, int8_t* __restrict__ k2,
    int8_t* __restrict__ v2t) {
  __shared__ __align__(16) int8_t Xs[64][80];
  __shared__ __align__(16) int8_t Ws[64][80];
  __shared__ float XS[64][65];
  __shared__ float meanS[64], denS[64];
  __shared__ __align__(16) int8_t Ot[64][80];

  const int g = blockIdx.x, rb = blockIdx.y;
  const int tid = threadIdx.x;
  const int w = tid >> 6, lane = tid & 63, quad = lane >> 4, c16 = lane & 15;
  const int row0 = rb * 64, col0 = g * 64;
  const int sr = tid >> 2, scol = (tid & 3) << 4;

  v4i acc[4];
#pragma unroll
  for (int s = 0; s < 4; s++) acc[s] = (v4i){0, 0, 0, 0};

  for (int k0 = 0; k0 < CC; k0 += 64) {
    int4 av = *(const int4*)(Aq + (size_t)(row0 + sr) * CC + k0 + scol);
    int4 wv = *(const int4*)(Wq + (size_t)(col0 + sr) * CC + k0 + scol);
    *(int4*)&Xs[sr][scol] = av;
    *(int4*)&Ws[sr][scol] = wv;
    __syncthreads();
    v4i xf = *(const v4i*)&Xs[16 * w + c16][quad * 16];
#pragma unroll
    for (int s = 0; s < 4; s++) {
      v4i wf = *(const v4i*)&Ws[16 * s + c16][quad * 16];
      acc[s] = __builtin_amdgcn_mfma_i32_16x16x64_i8(wf, xf, acc[s], 0, 0, 0);
    }
    __syncthreads();
  }

  const int which = g / HH, h = g % HH;
  const int b_idx = row0 >> 9, nbase = row0 & (NN - 1);
  const int m_loc = 16 * w + c16;  // tile-local sequence row
  const size_t bh = (size_t)b_idx * HH + h;

  if (which == 2) {  // v path: 3b quant, write transposed tile [d][n]
    const float a_in = scal[0], vact = scal[3];
#pragma unroll
    for (int s = 0; s < 4; s++)
#pragma unroll
      for (int r = 0; r < 4; r++) {
        int dcol = 16 * s + 4 * quad + r;
        int col = col0 + dcol;
        float vint = fadd((float)acc[s][r], biasq[col]);
        float va = fdiv(vact, fmul(a_in, qkv_alpha[col]));
        float t = fminf(fmaxf(fdiv(vint, va), -4.f), 3.f);
        Ot[dcol][m_loc] = (int8_t)rintf(t);
      }
    __syncthreads();
    int4 ov = *(const int4*)&Ot[sr][scol];
    *(int4*)(v2t + ((size_t)bh * HD + sr) * NN + nbase + scol) = ov;
  } else {  // q/k path: scaled LN + 3b quant
    float xs_loc[4][4];
#pragma unroll
    for (int s = 0; s < 4; s++)
#pragma unroll
      for (int r = 0; r < 4; r++) {
        int dcol = 16 * s + 4 * quad + r;
        int col = col0 + dcol;
        float vint = fadd((float)acc[s][r], biasq[col]);
        float x = fmul(vint, qkv_alpha[col]);
        xs_loc[s][r] = x;
        XS[m_loc][dcol] = x;
      }
    __syncthreads();
    if (tid < 64) np_stats_64(&XS[tid][0], &meanS[tid], &denS[tid]);
    __syncthreads();
    const float* ap = qparams + (which == 0 ? 0 : 128);
    float mean = meanS[m_loc], den = denS[m_loc];
#pragma unroll
    for (int s = 0; s < 4; s++) {
      uint32_t pack = 0;
#pragma unroll
      for (int r = 0; r < 4; r++) {
        int d = 16 * s + 4 * quad + r;
        float xn = fdiv(fsub(xs_loc[s][r], mean), den);
        float t = fdiv(fadd(xn, ap[64 + d]), ap[d]);
        t = fminf(fmaxf(t, -4.f), 3.f);
        pack |= ((uint32_t)(uint8_t)(int8_t)rintf(t)) << (8 * r);
      }
      *(uint32_t*)&Ot[m_loc][16 * s + 4 * quad] = pack;
    }
    __syncthreads();
    int8_t* dst = (which == 0) ? q2 : k2;
    int4 ov = *(const int4*)&Ot[sr][scol];
    *(int4*)(dst + ((size_t)bh * NN + nbase + sr) * HD + scol) = ov;
  }
}

// ---------------------------------------------------------------------------
// Attention (i8 MFMA), per (qtile64, b*h).  QK^T computed transposed
// (D2 = K_sub · Q^T): lane holds m = 16w+(lane&15), nn = 16f+4*quad+reg.
// Row sums of 2^m are exact in any order (all terms 2^m, m in [-4,4]) ->
// in-register shuffle reduction.  AV transposed (D = V_sub · attn^T) so the
// x1 epilogue packs 4 consecutive d per dword.
// ---------------------------------------------------------------------------
__global__ __launch_bounds__(256) void attn_kernel(
    const int8_t* __restrict__ q2, const int8_t* __restrict__ k2,
    const int8_t* __restrict__ v2t, const float* __restrict__ scal,
    int8_t* __restrict__ x1q) {
  __shared__ __align__(16) int8_t Qs[64][80];
  __shared__ __align__(16) int8_t Ks[64][80];
  __shared__ __align__(16) int8_t Vt[64][80];
  __shared__ __align__(16) int8_t At[64][80];
  __shared__ __align__(16) int8_t Xt[64][80];

  const int qt = blockIdx.x, bh = blockIdx.y;
  const int tid = threadIdx.x;
  const int w = tid >> 6, lane = tid & 63, quad = lane >> 4, c16 = lane & 15;
  const int sr = tid >> 2, scol = (tid & 3) << 4;
  const float attnm = scal[4];
  const float coef =
      fmul(1.4426950408889634f, fmul(fmul(0.125f, scal[1]), scal[2]));
  const float pa = fdiv(scal[5], fmul(attnm, scal[3]));
  const size_t base = (size_t)bh * NN * HD;

  *(int4*)&Qs[sr][scol] =
      *(const int4*)(q2 + base + (size_t)(qt * 64 + sr) * HD + scol);
  __syncthreads();
  v4i qf = *(const v4i*)&Qs[16 * w + c16][quad * 16];

  // ---- pass A: row sums of 2^m (order-independent, exact) ----
  float Srow = 0.f;
  for (int kt = 0; kt < 8; kt++) {
    *(int4*)&Ks[sr][scol] =
        *(const int4*)(k2 + base + (size_t)(kt * 64 + sr) * HD + scol);
    __syncthreads();
    float psum = 0.f;
#pragma unroll
    for (int f = 0; f < 4; f++) {
      v4i kf = *(const v4i*)&Ks[16 * f + c16][quad * 16];
      v4i d2 = (v4i){0, 0, 0, 0};
      d2 = __builtin_amdgcn_mfma_i32_16x16x64_i8(kf, qf, d2, 0, 0, 0);
#pragma unroll
      for (int r = 0; r < 4; r++) {
        float e = truncf(fmul(fmul(coef, (float)d2[r]), 128.f));
        int mm = (int)rintf(fmul(e, 0.0078125f));
        psum = fadd(psum, ldexpf(1.0f, mm));
      }
    }
    psum = fadd(psum, __shfl_xor(psum, 16, 64));
    psum = fadd(psum, __shfl_xor(psum, 32, 64));
    Srow = fadd(Srow, psum);
    __syncthreads();
  }

  // ---- pass B: requantize attn, AV ----
  v4i xacc[4];
#pragma unroll
  for (int s = 0; s < 4; s++) xacc[s] = (v4i){0, 0, 0, 0};

  for (int kt = 0; kt < 8; kt++) {
    *(int4*)&Ks[sr][scol] =
        *(const int4*)(k2 + base + (size_t)(kt * 64 + sr) * HD + scol);
    *(int4*)&Vt[sr][scol] =
        *(const int4*)(v2t + ((size_t)bh * HD + sr) * NN + kt * 64 + scol);
    __syncthreads();
#pragma unroll
    for (int f = 0; f < 4; f++) {
      v4i kf = *(const v4i*)&Ks[16 * f + c16][quad * 16];
      v4i d2 = (v4i){0, 0, 0, 0};
      d2 = __builtin_amdgcn_mfma_i32_16x16x64_i8(kf, qf, d2, 0, 0, 0);
      uint32_t pack = 0;
#pragma unroll
      for (int r = 0; r < 4; r++) {
        float e = truncf(fmul(fmul(coef, (float)d2[r]), 128.f));
        int mm = (int)rintf(fmul(e, 0.0078125f));
        float p = ldexpf(1.0f, mm);
        float t = fdiv(fdiv(p, Srow), attnm);
        t = fminf(fmaxf(t, 0.f), 7.f);
        pack |= ((uint32_t)(uint8_t)(int8_t)rintf(t)) << (8 * r);
      }
      *(uint32_t*)&At[16 * w + c16][16 * f + 4 * quad] = pack;
    }
    __syncthreads();
    v4i af = *(const v4i*)&At[16 * w + c16][quad * 16];
#pragma unroll
    for (int s = 0; s < 4; s++) {
      v4i vf = *(const v4i*)&Vt[16 * s + c16][quad * 16];
      xacc[s] = __builtin_amdgcn_mfma_i32_16x16x64_i8(vf, af, xacc[s], 0, 0, 0);
    }
    __syncthreads();
  }

  // epilogue: x1_q = round(clip(x1/pa, -4, 3)) -> [B,H,N,hd] int8
#pragma unroll
  for (int s = 0; s < 4; s++) {
    uint32_t pack = 0;
#pragma unroll
    for (int r = 0; r < 4; r++) {
      float t = fminf(fmaxf(fdiv((float)xacc[s][r], pa), -4.f), 3.f);
      pack |= ((uint32_t)(uint8_t)(int8_t)rintf(t)) << (8 * r);
    }
    *(uint32_t*)&Xt[16 * w + c16][16 * s + 4 * quad] = pack;
  }
  __syncthreads();
  int4 ov = *(const int4*)&Xt[sr][scol];
  *(int4*)(x1q + ((size_t)bh * NN + qt * 64 + sr) * HD + scol) = ov;
}

// ---------------------------------------------------------------------------
// GEMM2 (i8 MFMA): out = (x1q @ pwq^T) * proj_alpha * pact_m + proj_bias.
// x1q is [B,H,N,hd]; K-tile kt (64 wide) == head kt, so A staging reads
// contiguous 64B rows.  Epilogue: float4 stores (4 consecutive cols / lane).
// ---------------------------------------------------------------------------
__global__ __launch_bounds__(256) void gemm_proj_kernel(
    const int8_t* __restrict__ x1q, const int8_t* __restrict__ Wq,
    const float* __restrict__ proj_alpha, const float* __restrict__ proj_bias,
    const float* __restrict__ scal, float* __restrict__ out) {
  __shared__ __align__(16) int8_t Xs[64][80];
  __shared__ __align__(16) int8_t Ws[64][80];
  const int g = blockIdx.x, rb = blockIdx.y;
  const int tid = threadIdx.x;
  const int w = tid >> 6, lane = tid & 63, quad = lane >> 4, c16 = lane & 15;
  const int row0 = rb * 64, col0 = g * 64;
  const int b_idx = row0 >> 9, nbase = row0 & (NN - 1);
  const int sr = tid >> 2, scol = (tid & 3) << 4;

  v4i acc[4];
#pragma unroll
  for (int s = 0; s < 4; s++) acc[s] = (v4i){0, 0, 0, 0};

  for (int kt = 0; kt < 12; kt++) {  // head kt
    *(int4*)&Xs[sr][scol] = *(const int4*)(
        x1q + (((size_t)b_idx * HH + kt) * NN + nbase + sr) * HD + scol);
    *(int4*)&Ws[sr][scol] =
        *(const int4*)(Wq + (size_t)(col0 + sr) * CC + kt * 64 + scol);
    __syncthreads();
    v4i xf = *(const v4i*)&Xs[16 * w + c16][quad * 16];
#pragma unroll
    for (int s = 0; s < 4; s++) {
      v4i wf = *(const v4i*)&Ws[16 * s + c16][quad * 16];
      acc[s] = __builtin_amdgcn_mfma_i32_16x16x64_i8(wf, xf, acc[s], 0, 0, 0);
    }
    __syncthreads();
  }
  const float pact = scal[5];
  const int m = row0 + 16 * w + c16;
#pragma unroll
  for (int s = 0; s < 4; s++) {
    int colb = col0 + 16 * s + 4 * quad;
    float4 o;
    o.x = fadd(fmul(fmul((float)acc[s][0], proj_alpha[colb + 0]), pact),
               proj_bias[colb + 0]);
    o.y = fadd(fmul(fmul((float)acc[s][1], proj_alpha[colb + 1]), pact),
               proj_bias[colb + 1]);
    o.z = fadd(fmul(fmul((float)acc[s][2], proj_alpha[colb + 2]), pact),
               proj_bias[colb + 2]);
    o.w = fadd(fmul(fmul((float)acc[s][3], proj_alpha[colb + 3]), pact),
               proj_bias[colb + 3]);
    *(float4*)(out + (size_t)m * CC + colb) = o;
  }
}

extern "C" void kernel_launch(void* const* d_in, const int* in_sizes, int n_in,
                              void* d_out, int out_size, void* d_ws,
                              size_t ws_size, hipStream_t stream) {
  const float* x0 = (const float*)d_in[0];
  const float* qkv_w = (const float*)d_in[1];
  const float* qkv_alpha = (const float*)d_in[2];
  const float* qkv_bias = (const float*)d_in[3];
  const float* qkv_act_alpha = (const float*)d_in[4];
  const float* proj_w = (const float*)d_in[5];
  const float* proj_alpha = (const float*)d_in[6];
  const float* proj_bias = (const float*)d_in[7];
  const float* proj_act_alpha = (const float*)d_in[8];
  const float* normq_w = (const float*)d_in[9];
  const float* normq_b = (const float*)d_in[10];
  const float* normk_w = (const float*)d_in[11];
  const float* normk_b = (const float*)d_in[12];
  const float* qact_alpha = (const float*)d_in[13];
  const float* kact_alpha = (const float*)d_in[14];
  const float* vact_alpha = (const float*)d_in[15];
  const float* attnact_alpha = (const float*)d_in[16];

  char* ws = (char*)d_ws;
  size_t off = 0;
  auto alloc = [&](size_t bytes) -> char* {
    char* p = ws + off;
    off += (bytes + 255) & ~(size_t)255;
    return p;
  };
  float* scal = (float*)alloc(64 * 4);
  float* qparams = (float*)alloc(256 * 4);
  float* biasq = (float*)alloc(QKV_C * 4);
  int8_t* x0q = (int8_t*)alloc((size_t)M_ROWS * CC);
  int8_t* wq = (int8_t*)alloc((size_t)QKV_C * CC);
  int8_t* pwq = (int8_t*)alloc((size_t)CC * CC);
  int8_t* q2 = (int8_t*)alloc((size_t)BB * HH * NN * HD);
  int8_t* k2 = (int8_t*)alloc((size_t)BB * HH * NN * HD);
  int8_t* v2t = (int8_t*)alloc((size_t)BB * HH * NN * HD);
  int8_t* x1q = (int8_t*)alloc((size_t)M_ROWS * CC);

  prep_kernel<<<1, 256, 0, stream>>>(qkv_act_alpha, proj_act_alpha, qact_alpha,
                                     kact_alpha, vact_alpha, attnact_alpha,
                                     normq_w, normq_b, normk_w, normk_b,
                                     qkv_bias, qkv_alpha, scal, qparams, biasq);

  int total4 = M_ROWS * CC / 4;
  quant_x0_kernel<<<(total4 + 255) / 256, 256, 0, stream>>>(x0, scal, x0q,
                                                            total4);
  quant_w_kernel<<<(QKV_C * CC + 255) / 256, 256, 0, stream>>>(
      qkv_w, qkv_alpha, wq, QKV_C * CC);
  quant_w_kernel<<<(CC * CC + 255) / 256, 256, 0, stream>>>(proj_w, proj_alpha,
                                                            pwq, CC * CC);

  gemm_qkv_kernel<<<dim3(QKV_C / 64, M_ROWS / 64), 256, 0, stream>>>(
      x0q, wq, biasq, scal, qkv_alpha, qparams, q2, k2, v2t);

  attn_kernel<<<dim3(NN / 64, BB * HH), 256, 0, stream>>>(q2, k2, v2t, scal,
                                                          x1q);

  gemm_proj_kernel<<<dim3(CC / 64, M_ROWS / 64), 256, 0, stream>>>(
      x1q, pwq, proj_alpha, proj_bias, scal, (float*)d_out);
}

// Round 3
// 393.590 us; speedup vs baseline: 6.2060x; 1.1541x over previous
//
#include <hip/hip_runtime.h>
#include <stdint.h>

// ---------------------------------------------------------------------------
// Q_Attention: quantized ViT attention block, bit-faithful to the JAX/numpy ref.
// B=32, N=512, C=768, H=12, hd=64.  All GEMMs on i8 MFMA (int32 acc, exact).
// Sensitive fp ops use __f*_rn to pin IEEE fp32 semantics; reductions either
// replicate numpy pairwise order or are provably order-independent (2^m sums).
// Softmax divides are hoisted per-row (2^m scaling commutes with RN rounding).
// ---------------------------------------------------------------------------

#define BB 32
#define NN 512
#define CC 768
#define HH 12
#define HD 64
#define M_ROWS (BB * NN)     // 16384
#define QKV_C (3 * CC)       // 2304

typedef int v4i __attribute__((ext_vector_type(4)));

__device__ __forceinline__ float fadd(float a, float b) { return __fadd_rn(a, b); }
__device__ __forceinline__ float fmul(float a, float b) { return __fmul_rn(a, b); }
__device__ __forceinline__ float fdiv(float a, float b) { return __fdiv_rn(a, b); }
__device__ __forceinline__ float fsub(float a, float b) { return __fsub_rn(a, b); }

// numpy pairwise_sum, n=96 (no remainder): 8 accumulators, then pairwise combine
__device__ float np_sum_96(const float* a) {
  float r[8];
#pragma unroll
  for (int j = 0; j < 8; j++) r[j] = a[j];
  for (int i = 8; i < 96; i += 8)
#pragma unroll
    for (int j = 0; j < 8; j++) r[j] = fadd(r[j], a[i + j]);
  return fadd(fadd(fadd(r[0], r[1]), fadd(r[2], r[3])),
              fadd(fadd(r[4], r[5]), fadd(r[6], r[7])));
}

// numpy pairwise mean of 768: 768->384->192->96 tree
__device__ float np_mean_768(const float* a) {
  float s0 = fadd(fadd(np_sum_96(a), np_sum_96(a + 96)),
                  fadd(np_sum_96(a + 192), np_sum_96(a + 288)));
  float s1 = fadd(fadd(np_sum_96(a + 384), np_sum_96(a + 480)),
                  fadd(np_sum_96(a + 576), np_sum_96(a + 672)));
  return fdiv(fadd(s0, s1), 768.0f);
}

// numpy pairwise mean of 12: 8-acc combine + 4 sequential remainder adds
__device__ float np_mean_12(const float* a) {
  float r[8];
#pragma unroll
  for (int j = 0; j < 8; j++) r[j] = a[j];
  float res = fadd(fadd(fadd(r[0], r[1]), fadd(r[2], r[3])),
                   fadd(fadd(r[4], r[5]), fadd(r[6], r[7])));
  res = fadd(res, a[8]);
  res = fadd(res, a[9]);
  res = fadd(res, a[10]);
  res = fadd(res, a[11]);
  return fdiv(res, 12.0f);
}

// numpy-order mean + (std(ddof=1)+1e-5) over 64 contiguous values
__device__ void np_stats_64(const float* x, float* mean_out, float* den_out) {
  float r[8];
#pragma unroll
  for (int j = 0; j < 8; j++) r[j] = x[j];
  for (int i = 8; i < 64; i += 8)
#pragma unroll
    for (int j = 0; j < 8; j++) r[j] = fadd(r[j], x[i + j]);
  float s = fadd(fadd(fadd(r[0], r[1]), fadd(r[2], r[3])),
                 fadd(fadd(r[4], r[5]), fadd(r[6], r[7])));
  float mean = fdiv(s, 64.0f);
#pragma unroll
  for (int j = 0; j < 8; j++) {
    float d = fsub(x[j], mean);
    r[j] = fmul(d, d);
  }
  for (int i = 8; i < 64; i += 8)
#pragma unroll
    for (int j = 0; j < 8; j++) {
      float d = fsub(x[i + j], mean);
      r[j] = fadd(r[j], fmul(d, d));
    }
  float ss = fadd(fadd(fadd(r[0], r[1]), fadd(r[2], r[3])),
                  fadd(fadd(r[4], r[5]), fadd(r[6], r[7])));
  float var = fdiv(ss, 63.0f);
  float sd = __fsqrt_rn(var);
  *mean_out = mean;
  *den_out = fadd(sd, 1e-5f);
}

// ---------------------------------------------------------------------------
// prep: scalar means + folded LN quant params + integer qkv bias
// scal: [0]=a_in [1]=qact_m [2]=kact_m [3]=vact_m [4]=attnact_m [5]=pact_m
// qparams: [0:64]=qalpha [64:128]=qbias [128:192]=kalpha [192:256]=kbias
// ---------------------------------------------------------------------------
__global__ void prep_kernel(const float* __restrict__ qkv_act_alpha,
                            const float* __restrict__ proj_act_alpha,
                            const float* __restrict__ qact_alpha,
                            const float* __restrict__ kact_alpha,
                            const float* __restrict__ vact_alpha,
                            const float* __restrict__ attnact_alpha,
                            const float* __restrict__ normq_w,
                            const float* __restrict__ normq_b,
                            const float* __restrict__ normk_w,
                            const float* __restrict__ normk_b,
                            const float* __restrict__ qkv_bias,
                            const float* __restrict__ qkv_alpha,
                            float* __restrict__ scal,
                            float* __restrict__ qparams,
                            float* __restrict__ biasq) {
  __shared__ float s_scal[8];
  int tid = threadIdx.x;
  if (tid == 0) s_scal[0] = np_mean_768(qkv_act_alpha);
  if (tid == 1) s_scal[5] = np_mean_768(proj_act_alpha);
  if (tid == 2) s_scal[1] = np_mean_12(qact_alpha);
  if (tid == 3) s_scal[2] = np_mean_12(kact_alpha);
  if (tid == 4) s_scal[3] = np_mean_12(vact_alpha);
  if (tid == 5) s_scal[4] = np_mean_12(attnact_alpha);
  __syncthreads();
  if (tid < 6) scal[tid] = s_scal[tid];
  if (tid < 64) {
    qparams[tid]       = fdiv(s_scal[1], normq_w[tid]);    // act_a / nw
    qparams[64 + tid]  = fdiv(normq_b[tid], normq_w[tid]); // nb / nw
    qparams[128 + tid] = fdiv(s_scal[2], normk_w[tid]);
    qparams[192 + tid] = fdiv(normk_b[tid], normk_w[tid]);
  }
  float a_in = s_scal[0];
  for (int c = tid; c < QKV_C; c += blockDim.x)
    biasq[c] = truncf(fdiv(fdiv(qkv_bias[c], a_in), qkv_alpha[c]));
}

// x0_q = round(clip(x0 / a_in, -8, 7)) -> int8
__global__ void quant_x0_kernel(const float* __restrict__ x0,
                                const float* __restrict__ scal,
                                int8_t* __restrict__ x0q, int total4) {
  int i = blockIdx.x * blockDim.x + threadIdx.x;
  if (i >= total4) return;
  float a_in = scal[0];
  float4 v = ((const float4*)x0)[i];
  char4 o;
  o.x = (int8_t)rintf(fminf(fmaxf(fdiv(v.x, a_in), -8.f), 7.f));
  o.y = (int8_t)rintf(fminf(fmaxf(fdiv(v.y, a_in), -8.f), 7.f));
  o.z = (int8_t)rintf(fminf(fmaxf(fdiv(v.z, a_in), -8.f), 7.f));
  o.w = (int8_t)rintf(fminf(fmaxf(fdiv(v.w, a_in), -8.f), 7.f));
  ((char4*)x0q)[i] = o;
}

// row-wise 4-bit weight quant: wq = round(clip(w / alpha[row], -8, 7))
__global__ void quant_w_kernel(const float* __restrict__ w,
                               const float* __restrict__ alpha,
                               int8_t* __restrict__ wq, int total) {
  int i = blockIdx.x * blockDim.x + threadIdx.x;
  if (i >= total) return;
  int row = i / CC;
  float t = fminf(fmaxf(fdiv(w[i], alpha[row]), -8.f), 7.f);
  wq[i] = (int8_t)rintf(t);
}

// ---------------------------------------------------------------------------
// GEMM1 (i8 MFMA, transposed orientation D = W·X^T):
//   qkv-int = x0q @ wq^T + biasq, fused epilogues:
//   q/k: scaled LayerNorm + 3b quant -> q2/k2 int8 [B,H,N,hd]
//   v:   3b quant -> v2t int8 [B,H,hd,N]   (pre-transposed for AV staging)
// LDS overlay: fp32 XS stats array reuses the (dead) staging tiles after the
// K-loop -> 22272 B -> 7 blocks/CU (was 33792 B -> 4).  Register prefetch of
// the next K-tile overlaps global latency with MFMA + barrier.
// ---------------------------------------------------------------------------
__global__ __launch_bounds__(256) void gemm_qkv_kernel(
    const int8_t* __restrict__ Aq, const int8_t* __restrict__ Wq,
    const float* __restrict__ biasq, const float* __restrict__ scal,
    const float* __restrict__ qkv_alpha, const float* __restrict__ qparams,
    int8_t* __restrict__ q2, int8_t* __restrict__ k2,
    int8_t* __restrict__ v2t) {
  __shared__ __align__(16) char smem[22272];
  int8_t (*Xs)[80] = (int8_t(*)[80])smem;            // phase 1: 5120
  int8_t (*Ws)[80] = (int8_t(*)[80])(smem + 5120);   // phase 1: 5120
  float (*XS)[65] = (float(*)[65])smem;              // phase 2: 16640
  float* meanS = (float*)(smem + 16640);             // 256
  float* denS = (float*)(smem + 16896);              // 256
  int8_t (*Ot)[80] = (int8_t(*)[80])(smem + 17152);  // 5120 (no overlap w/ XS)

  const int g = blockIdx.x, rb = blockIdx.y;
  const int tid = threadIdx.x;
  const int w = tid >> 6, lane = tid & 63, quad = lane >> 4, c16 = lane & 15;
  const int row0 = rb * 64, col0 = g * 64;
  const int sr = tid >> 2, scol = (tid & 3) << 4;

  v4i acc[4];
#pragma unroll
  for (int s = 0; s < 4; s++) acc[s] = (v4i){0, 0, 0, 0};

  int4 av = *(const int4*)(Aq + (size_t)(row0 + sr) * CC + scol);
  int4 wv = *(const int4*)(Wq + (size_t)(col0 + sr) * CC + scol);
  for (int k0 = 0; k0 < CC; k0 += 64) {
    *(int4*)&Xs[sr][scol] = av;
    *(int4*)&Ws[sr][scol] = wv;
    __syncthreads();
    if (k0 + 64 < CC) {
      av = *(const int4*)(Aq + (size_t)(row0 + sr) * CC + k0 + 64 + scol);
      wv = *(const int4*)(Wq + (size_t)(col0 + sr) * CC + k0 + 64 + scol);
    }
    v4i xf = *(const v4i*)&Xs[16 * w + c16][quad * 16];
#pragma unroll
    for (int s = 0; s < 4; s++) {
      v4i wf = *(const v4i*)&Ws[16 * s + c16][quad * 16];
      acc[s] = __builtin_amdgcn_mfma_i32_16x16x64_i8(wf, xf, acc[s], 0, 0, 0);
    }
    __syncthreads();  // after this, Xs/Ws are dead -> XS overlay is safe
  }

  const int which = g / HH, h = g % HH;
  const int b_idx = row0 >> 9, nbase = row0 & (NN - 1);
  const int m_loc = 16 * w + c16;  // tile-local sequence row
  const size_t bh = (size_t)b_idx * HH + h;

  if (which == 2) {  // v path: 3b quant, write transposed tile [d][n]
    const float a_in = scal[0], vact = scal[3];
#pragma unroll
    for (int s = 0; s < 4; s++)
#pragma unroll
      for (int r = 0; r < 4; r++) {
        int dcol = 16 * s + 4 * quad + r;
        int col = col0 + dcol;
        float vint = fadd((float)acc[s][r], biasq[col]);
        float va = fdiv(vact, fmul(a_in, qkv_alpha[col]));
        float t = fminf(fmaxf(fdiv(vint, va), -4.f), 3.f);
        Ot[dcol][m_loc] = (int8_t)rintf(t);
      }
    __syncthreads();
    int4 ov = *(const int4*)&Ot[sr][scol];
    *(int4*)(v2t + ((size_t)bh * HD + sr) * NN + nbase + scol) = ov;
  } else {  // q/k path: scaled LN + 3b quant
    float xs_loc[4][4];
#pragma unroll
    for (int s = 0; s < 4; s++)
#pragma unroll
      for (int r = 0; r < 4; r++) {
        int dcol = 16 * s + 4 * quad + r;
        int col = col0 + dcol;
        float vint = fadd((float)acc[s][r], biasq[col]);
        float x = fmul(vint, qkv_alpha[col]);
        xs_loc[s][r] = x;
        XS[m_loc][dcol] = x;
      }
    __syncthreads();
    if (tid < 64) np_stats_64(&XS[tid][0], &meanS[tid], &denS[tid]);
    __syncthreads();
    const float* ap = qparams + (which == 0 ? 0 : 128);
    float mean = meanS[m_loc], den = denS[m_loc];
#pragma unroll
    for (int s = 0; s < 4; s++) {
      uint32_t pack = 0;
#pragma unroll
      for (int r = 0; r < 4; r++) {
        int d = 16 * s + 4 * quad + r;
        float xn = fdiv(fsub(xs_loc[s][r], mean), den);
        float t = fdiv(fadd(xn, ap[64 + d]), ap[d]);
        t = fminf(fmaxf(t, -4.f), 3.f);
        pack |= ((uint32_t)(uint8_t)(int8_t)rintf(t)) << (8 * r);
      }
      *(uint32_t*)&Ot[m_loc][16 * s + 4 * quad] = pack;
    }
    __syncthreads();
    int8_t* dst = (which == 0) ? q2 : k2;
    int4 ov = *(const int4*)&Ot[sr][scol];
    *(int4*)(dst + ((size_t)bh * NN + nbase + sr) * HD + scol) = ov;
  }
}

// ---------------------------------------------------------------------------
// Attention (i8 MFMA), per (qtile64, b*h).  QK^T computed transposed
// (D2 = K_sub·Q^T): lane holds Q-row m=16w+(lane&15), K-index 16f+4*quad+r.
// Pass A: QK MFMA + m=rint(trunc(coef128*qk)/128) kept PACKED IN REGISTERS
// (8kt x 4 dwords); row sum of 2^m exact in any order (terms 2^m, m in
// [-4,4]) -> shuffle reduce.  Pass B: no K reload / no QK recompute;
// weight = rint(min(ldexp(u, m), 7)) with u = (1/S)/attnm hoisted per row
// (exact: power-of-2 scaling commutes with RN rounding).  AV transposed.
// ---------------------------------------------------------------------------
__global__ __launch_bounds__(256) void attn_kernel(
    const int8_t* __restrict__ q2, const int8_t* __restrict__ k2,
    const int8_t* __restrict__ v2t, const float* __restrict__ scal,
    int8_t* __restrict__ x1q) {
  __shared__ __align__(16) int8_t Qs[64][80];
  __shared__ __align__(16) int8_t Ks[64][80];  // K tiles pass A; Xt epilogue
  __shared__ __align__(16) int8_t Vt[64][80];
  __shared__ __align__(16) int8_t At[64][80];

  const int qt = blockIdx.x, bh = blockIdx.y;
  const int tid = threadIdx.x;
  const int w = tid >> 6, lane = tid & 63, quad = lane >> 4, c16 = lane & 15;
  const int sr = tid >> 2, scol = (tid & 3) << 4;
  const float attnm = scal[4];
  const float coef =
      fmul(1.4426950408889634f, fmul(fmul(0.125f, scal[1]), scal[2]));
  const float coef128 = fmul(coef, 128.f);  // exact pow2 scale
  const size_t base = (size_t)bh * NN * HD;

  *(int4*)&Qs[sr][scol] =
      *(const int4*)(q2 + base + (size_t)(qt * 64 + sr) * HD + scol);
  __syncthreads();
  v4i qf = *(const v4i*)&Qs[16 * w + c16][quad * 16];

  // ---- pass A: QK^T, m -> registers, row sums of 2^m ----
  uint32_t mpack[8][4];
  float Srow = 0.f;
  int4 kv = *(const int4*)(k2 + base + (size_t)sr * HD + scol);
#pragma unroll
  for (int kt = 0; kt < 8; kt++) {
    *(int4*)&Ks[sr][scol] = kv;
    __syncthreads();
    if (kt < 7)
      kv = *(const int4*)(k2 + base + (size_t)((kt + 1) * 64 + sr) * HD + scol);
    float psum = 0.f;
#pragma unroll
    for (int f = 0; f < 4; f++) {
      v4i kf = *(const v4i*)&Ks[16 * f + c16][quad * 16];
      v4i d2 = (v4i){0, 0, 0, 0};
      d2 = __builtin_amdgcn_mfma_i32_16x16x64_i8(kf, qf, d2, 0, 0, 0);
      uint32_t pk = 0;
#pragma unroll
      for (int r = 0; r < 4; r++) {
        float e = truncf(fmul(coef128, (float)d2[r]));
        int mi = (int)rintf(fmul(e, 0.0078125f));
        psum = fadd(psum, ldexpf(1.0f, mi));
        pk |= ((uint32_t)(uint8_t)(int8_t)mi) << (8 * r);
      }
      mpack[kt][f] = pk;
    }
    psum = fadd(psum, __shfl_xor(psum, 16, 64));
    psum = fadd(psum, __shfl_xor(psum, 32, 64));
    Srow = fadd(Srow, psum);
    __syncthreads();
  }
  const float u = fdiv(fdiv(1.0f, Srow), attnm);  // per-row, hoisted divides

  // ---- pass B: requantize from register m, AV ----
  v4i xacc[4];
#pragma unroll
  for (int s = 0; s < 4; s++) xacc[s] = (v4i){0, 0, 0, 0};

  int4 vv = *(const int4*)(v2t + ((size_t)bh * HD + sr) * NN + scol);
#pragma unroll
  for (int kt = 0; kt < 8; kt++) {
    *(int4*)&Vt[sr][scol] = vv;
    __syncthreads();
    if (kt < 7)
      vv = *(const int4*)(v2t + ((size_t)bh * HD + sr) * NN + (kt + 1) * 64 +
                          scol);
#pragma unroll
    for (int f = 0; f < 4; f++) {
      uint32_t pk = mpack[kt][f];
      uint32_t wpk = 0;
#pragma unroll
      for (int r = 0; r < 4; r++) {
        int mi = (int)(int8_t)(pk >> (8 * r));
        float t = fminf(ldexpf(u, mi), 7.f);  // >0 so low clip never binds
        wpk |= ((uint32_t)(uint8_t)(int8_t)rintf(t)) << (8 * r);
      }
      *(uint32_t*)&At[16 * w + c16][16 * f + 4 * quad] = wpk;
    }
    // At rows are wave-private: only need LDS drain, not a full barrier
    asm volatile("s_waitcnt lgkmcnt(0)" ::: "memory");
    v4i af = *(const v4i*)&At[16 * w + c16][quad * 16];
#pragma unroll
    for (int s = 0; s < 4; s++) {
      v4i vf = *(const v4i*)&Vt[16 * s + c16][quad * 16];
      xacc[s] = __builtin_amdgcn_mfma_i32_16x16x64_i8(vf, af, xacc[s], 0, 0, 0);
    }
    __syncthreads();
  }

  // epilogue: x1_q = round(clip(x1/pa, -4, 3)) -> [B,H,N,hd] int8 (Xt := Ks)
  const float pa = fdiv(scal[5], fmul(attnm, scal[3]));
#pragma unroll
  for (int s = 0; s < 4; s++) {
    uint32_t pack = 0;
#pragma unroll
    for (int r = 0; r < 4; r++) {
      float t = fminf(fmaxf(fdiv((float)xacc[s][r], pa), -4.f), 3.f);
      pack |= ((uint32_t)(uint8_t)(int8_t)rintf(t)) << (8 * r);
    }
    *(uint32_t*)&Ks[16 * w + c16][16 * s + 4 * quad] = pack;
  }
  __syncthreads();
  int4 ov = *(const int4*)&Ks[sr][scol];
  *(int4*)(x1q + ((size_t)bh * NN + qt * 64 + sr) * HD + scol) = ov;
}

// ---------------------------------------------------------------------------
// GEMM2 (i8 MFMA): out = (x1q @ pwq^T) * proj_alpha * pact_m + proj_bias.
// x1q is [B,H,N,hd]; K-tile kt (64 wide) == head kt -> contiguous 64B rows.
// Register prefetch of next K-tile; float4 epilogue stores.
// ---------------------------------------------------------------------------
__global__ __launch_bounds__(256) void gemm_proj_kernel(
    const int8_t* __restrict__ x1q, const int8_t* __restrict__ Wq,
    const float* __restrict__ proj_alpha, const float* __restrict__ proj_bias,
    const float* __restrict__ scal, float* __restrict__ out) {
  __shared__ __align__(16) int8_t Xs[64][80];
  __shared__ __align__(16) int8_t Ws[64][80];
  const int g = blockIdx.x, rb = blockIdx.y;
  const int tid = threadIdx.x;
  const int w = tid >> 6, lane = tid & 63, quad = lane >> 4, c16 = lane & 15;
  const int row0 = rb * 64, col0 = g * 64;
  const int b_idx = row0 >> 9, nbase = row0 & (NN - 1);
  const int sr = tid >> 2, scol = (tid & 3) << 4;

  v4i acc[4];
#pragma unroll
  for (int s = 0; s < 4; s++) acc[s] = (v4i){0, 0, 0, 0};

  int4 av = *(const int4*)(x1q + (((size_t)b_idx * HH) * NN + nbase + sr) * HD +
                           scol);
  int4 wv = *(const int4*)(Wq + (size_t)(col0 + sr) * CC + scol);
  for (int kt = 0; kt < 12; kt++) {  // head kt
    *(int4*)&Xs[sr][scol] = av;
    *(int4*)&Ws[sr][scol] = wv;
    __syncthreads();
    if (kt + 1 < 12) {
      av = *(const int4*)(x1q +
                          (((size_t)b_idx * HH + kt + 1) * NN + nbase + sr) *
                              HD +
                          scol);
      wv = *(const int4*)(Wq + (size_t)(col0 + sr) * CC + (kt + 1) * 64 + scol);
    }
    v4i xf = *(const v4i*)&Xs[16 * w + c16][quad * 16];
#pragma unroll
    for (int s = 0; s < 4; s++) {
      v4i wf = *(const v4i*)&Ws[16 * s + c16][quad * 16];
      acc[s] = __builtin_amdgcn_mfma_i32_16x16x64_i8(wf, xf, acc[s], 0, 0, 0);
    }
    __syncthreads();
  }
  const float pact = scal[5];
  const int m = row0 + 16 * w + c16;
#pragma unroll
  for (int s = 0; s < 4; s++) {
    int colb = col0 + 16 * s + 4 * quad;
    float4 o;
    o.x = fadd(fmul(fmul((float)acc[s][0], proj_alpha[colb + 0]), pact),
               proj_bias[colb + 0]);
    o.y = fadd(fmul(fmul((float)acc[s][1], proj_alpha[colb + 1]), pact),
               proj_bias[colb + 1]);
    o.z = fadd(fmul(fmul((float)acc[s][2], proj_alpha[colb + 2]), pact),
               proj_bias[colb + 2]);
    o.w = fadd(fmul(fmul((float)acc[s][3], proj_alpha[colb + 3]), pact),
               proj_bias[colb + 3]);
    *(float4*)(out + (size_t)m * CC + colb) = o;
  }
}

extern "C" void kernel_launch(void* const* d_in, const int* in_sizes, int n_in,
                              void* d_out, int out_size, void* d_ws,
                              size_t ws_size, hipStream_t stream) {
  const float* x0 = (const float*)d_in[0];
  const float* qkv_w = (const float*)d_in[1];
  const float* qkv_alpha = (const float*)d_in[2];
  const float* qkv_bias = (const float*)d_in[3];
  const float* qkv_act_alpha = (const float*)d_in[4];
  const float* proj_w = (const float*)d_in[5];
  const float* proj_alpha = (const float*)d_in[6];
  const float* proj_bias = (const float*)d_in[7];
  const float* proj_act_alpha = (const float*)d_in[8];
  const float* normq_w = (const float*)d_in[9];
  const float* normq_b = (const float*)d_in[10];
  const float* normk_w = (const float*)d_in[11];
  const float* normk_b = (const float*)d_in[12];
  const float* qact_alpha = (const float*)d_in[13];
  const float* kact_alpha = (const float*)d_in[14];
  const float* vact_alpha = (const float*)d_in[15];
  const float* attnact_alpha = (const float*)d_in[16];

  char* ws = (char*)d_ws;
  size_t off = 0;
  auto alloc = [&](size_t bytes) -> char* {
    char* p = ws + off;
    off += (bytes + 255) & ~(size_t)255;
    return p;
  };
  float* scal = (float*)alloc(64 * 4);
  float* qparams = (float*)alloc(256 * 4);
  float* biasq = (float*)alloc(QKV_C * 4);
  int8_t* x0q = (int8_t*)alloc((size_t)M_ROWS * CC);
  int8_t* wq = (int8_t*)alloc((size_t)QKV_C * CC);
  int8_t* pwq = (int8_t*)alloc((size_t)CC * CC);
  int8_t* q2 = (int8_t*)alloc((size_t)BB * HH * NN * HD);
  int8_t* k2 = (int8_t*)alloc((size_t)BB * HH * NN * HD);
  int8_t* v2t = (int8_t*)alloc((size_t)BB * HH * NN * HD);
  int8_t* x1q = (int8_t*)alloc((size_t)M_ROWS * CC);

  prep_kernel<<<1, 256, 0, stream>>>(qkv_act_alpha, proj_act_alpha, qact_alpha,
                                     kact_alpha, vact_alpha, attnact_alpha,
                                     normq_w, normq_b, normk_w, normk_b,
                                     qkv_bias, qkv_alpha, scal, qparams, biasq);

  int total4 = M_ROWS * CC / 4;
  quant_x0_kernel<<<(total4 + 255) / 256, 256, 0, stream>>>(x0, scal, x0q,
                                                            total4);
  quant_w_kernel<<<(QKV_C * CC + 255) / 256, 256, 0, stream>>>(
      qkv_w, qkv_alpha, wq, QKV_C * CC);
  quant_w_kernel<<<(CC * CC + 255) / 256, 256, 0, stream>>>(proj_w, proj_alpha,
                                                            pwq, CC * CC);

  gemm_qkv_kernel<<<dim3(QKV_C / 64, M_ROWS / 64), 256, 0, stream>>>(
      x0q, wq, biasq, scal, qkv_alpha, qparams, q2, k2, v2t);

  attn_kernel<<<dim3(NN / 64, BB * HH), 256, 0, stream>>>(q2, k2, v2t, scal,
                                                          x1q);

  gemm_proj_kernel<<<dim3(CC / 64, M_ROWS / 64), 256, 0, stream>>>(
      x1q, pwq, proj_alpha, proj_bias, scal, (float*)d_out);
}

// Round 4
// 371.040 us; speedup vs baseline: 6.5832x; 1.0608x over previous
//
#include <hip/hip_runtime.h>
#include <stdint.h>

// ---------------------------------------------------------------------------
// Q_Attention: quantized ViT attention block, bit-faithful to the JAX/numpy ref.
// B=32, N=512, C=768, H=12, hd=64.  All GEMMs on i8 MFMA (int32 acc, exact).
// Sensitive fp ops use __f*_rn to pin IEEE fp32 semantics; reductions either
// replicate numpy pairwise order or are provably order-independent (2^m sums).
// R4: 128x128 GEMM tiles (64x64/wave, 16 MFMA per 8 ds_read_b128), double-
// buffered staging, head-phased LN epilogue, V-transpose via swapped-operand
// MFMA (X*W^T) so transposed output packs into dwords.
// ---------------------------------------------------------------------------

#define BB 32
#define NN 512
#define CC 768
#define HH 12
#define HD 64
#define M_ROWS (BB * NN)     // 16384
#define QKV_C (3 * CC)       // 2304

typedef int v4i __attribute__((ext_vector_type(4)));

__device__ __forceinline__ float fadd(float a, float b) { return __fadd_rn(a, b); }
__device__ __forceinline__ float fmul(float a, float b) { return __fmul_rn(a, b); }
__device__ __forceinline__ float fdiv(float a, float b) { return __fdiv_rn(a, b); }
__device__ __forceinline__ float fsub(float a, float b) { return __fsub_rn(a, b); }

// numpy pairwise_sum, n=96 (no remainder): 8 accumulators, then pairwise combine
__device__ float np_sum_96(const float* a) {
  float r[8];
#pragma unroll
  for (int j = 0; j < 8; j++) r[j] = a[j];
  for (int i = 8; i < 96; i += 8)
#pragma unroll
    for (int j = 0; j < 8; j++) r[j] = fadd(r[j], a[i + j]);
  return fadd(fadd(fadd(r[0], r[1]), fadd(r[2], r[3])),
              fadd(fadd(r[4], r[5]), fadd(r[6], r[7])));
}

// numpy pairwise mean of 12: 8-acc combine + 4 sequential remainder adds
__device__ float np_mean_12(const float* a) {
  float r[8];
#pragma unroll
  for (int j = 0; j < 8; j++) r[j] = a[j];
  float res = fadd(fadd(fadd(r[0], r[1]), fadd(r[2], r[3])),
                   fadd(fadd(r[4], r[5]), fadd(r[6], r[7])));
  res = fadd(res, a[8]);
  res = fadd(res, a[9]);
  res = fadd(res, a[10]);
  res = fadd(res, a[11]);
  return fdiv(res, 12.0f);
}

// numpy-order mean + (std(ddof=1)+1e-5) over a 16B-aligned 64-float LDS row.
// float4 loads; op sequence identical to the scalar version (bit-exact).
__device__ void np_stats_64_v4(const float* x, float* mean_out, float* den_out) {
  const float4* xv = (const float4*)x;
  float r[8];
  {
    float4 a = xv[0], b = xv[1];
    r[0] = a.x; r[1] = a.y; r[2] = a.z; r[3] = a.w;
    r[4] = b.x; r[5] = b.y; r[6] = b.z; r[7] = b.w;
  }
#pragma unroll
  for (int i = 2; i < 16; i += 2) {
    float4 a = xv[i], b = xv[i + 1];
    r[0] = fadd(r[0], a.x); r[1] = fadd(r[1], a.y);
    r[2] = fadd(r[2], a.z); r[3] = fadd(r[3], a.w);
    r[4] = fadd(r[4], b.x); r[5] = fadd(r[5], b.y);
    r[6] = fadd(r[6], b.z); r[7] = fadd(r[7], b.w);
  }
  float s = fadd(fadd(fadd(r[0], r[1]), fadd(r[2], r[3])),
                 fadd(fadd(r[4], r[5]), fadd(r[6], r[7])));
  float mean = fdiv(s, 64.0f);
  {
    float4 a = xv[0], b = xv[1];
    float d0 = fsub(a.x, mean), d1 = fsub(a.y, mean), d2 = fsub(a.z, mean),
          d3 = fsub(a.w, mean), d4 = fsub(b.x, mean), d5 = fsub(b.y, mean),
          d6 = fsub(b.z, mean), d7 = fsub(b.w, mean);
    r[0] = fmul(d0, d0); r[1] = fmul(d1, d1); r[2] = fmul(d2, d2);
    r[3] = fmul(d3, d3); r[4] = fmul(d4, d4); r[5] = fmul(d5, d5);
    r[6] = fmul(d6, d6); r[7] = fmul(d7, d7);
  }
#pragma unroll
  for (int i = 2; i < 16; i += 2) {
    float4 a = xv[i], b = xv[i + 1];
    float d0 = fsub(a.x, mean), d1 = fsub(a.y, mean), d2 = fsub(a.z, mean),
          d3 = fsub(a.w, mean), d4 = fsub(b.x, mean), d5 = fsub(b.y, mean),
          d6 = fsub(b.z, mean), d7 = fsub(b.w, mean);
    r[0] = fadd(r[0], fmul(d0, d0)); r[1] = fadd(r[1], fmul(d1, d1));
    r[2] = fadd(r[2], fmul(d2, d2)); r[3] = fadd(r[3], fmul(d3, d3));
    r[4] = fadd(r[4], fmul(d4, d4)); r[5] = fadd(r[5], fmul(d5, d5));
    r[6] = fadd(r[6], fmul(d6, d6)); r[7] = fadd(r[7], fmul(d7, d7));
  }
  float ss = fadd(fadd(fadd(r[0], r[1]), fadd(r[2], r[3])),
                  fadd(fadd(r[4], r[5]), fadd(r[6], r[7])));
  float var = fdiv(ss, 63.0f);
  float sd = __fsqrt_rn(var);
  *mean_out = mean;
  *den_out = fadd(sd, 1e-5f);
}

// ---------------------------------------------------------------------------
// prep: scalar means + folded LN quant params + integer qkv bias
// scal: [0]=a_in [1]=qact_m [2]=kact_m [3]=vact_m [4]=attnact_m [5]=pact_m
// qparams: [0:64]=qalpha [64:128]=qbias [128:192]=kalpha [192:256]=kbias
// 768-means parallelized: 8 threads each np_sum_96, combine in numpy tree order.
// ---------------------------------------------------------------------------
__global__ void prep_kernel(const float* __restrict__ qkv_act_alpha,
                            const float* __restrict__ proj_act_alpha,
                            const float* __restrict__ qact_alpha,
                            const float* __restrict__ kact_alpha,
                            const float* __restrict__ vact_alpha,
                            const float* __restrict__ attnact_alpha,
                            const float* __restrict__ normq_w,
                            const float* __restrict__ normq_b,
                            const float* __restrict__ normk_w,
                            const float* __restrict__ normk_b,
                            const float* __restrict__ qkv_bias,
                            const float* __restrict__ qkv_alpha,
                            float* __restrict__ scal,
                            float* __restrict__ qparams,
                            float* __restrict__ biasq) {
  __shared__ float s_scal[8];
  __shared__ float chunk[16];
  int tid = threadIdx.x;
  if (tid < 8) chunk[tid] = np_sum_96(qkv_act_alpha + 96 * tid);
  else if (tid < 16) chunk[tid] = np_sum_96(proj_act_alpha + 96 * (tid - 8));
  if (tid == 16) s_scal[1] = np_mean_12(qact_alpha);
  if (tid == 17) s_scal[2] = np_mean_12(kact_alpha);
  if (tid == 18) s_scal[3] = np_mean_12(vact_alpha);
  if (tid == 19) s_scal[4] = np_mean_12(attnact_alpha);
  __syncthreads();
  if (tid == 0) {
    float s0 = fadd(fadd(chunk[0], chunk[1]), fadd(chunk[2], chunk[3]));
    float s1 = fadd(fadd(chunk[4], chunk[5]), fadd(chunk[6], chunk[7]));
    s_scal[0] = fdiv(fadd(s0, s1), 768.0f);
    float p0 = fadd(fadd(chunk[8], chunk[9]), fadd(chunk[10], chunk[11]));
    float p1 = fadd(fadd(chunk[12], chunk[13]), fadd(chunk[14], chunk[15]));
    s_scal[5] = fdiv(fadd(p0, p1), 768.0f);
  }
  __syncthreads();
  if (tid < 6) scal[tid] = s_scal[tid];
  if (tid < 64) {
    qparams[tid]       = fdiv(s_scal[1], normq_w[tid]);    // act_a / nw
    qparams[64 + tid]  = fdiv(normq_b[tid], normq_w[tid]); // nb / nw
    qparams[128 + tid] = fdiv(s_scal[2], normk_w[tid]);
    qparams[192 + tid] = fdiv(normk_b[tid], normk_w[tid]);
  }
  float a_in = s_scal[0];
  for (int c = tid; c < QKV_C; c += blockDim.x)
    biasq[c] = truncf(fdiv(fdiv(qkv_bias[c], a_in), qkv_alpha[c]));
}

// x0_q = round(clip(x0 / a_in, -8, 7)) -> int8
__global__ void quant_x0_kernel(const float* __restrict__ x0,
                                const float* __restrict__ scal,
                                int8_t* __restrict__ x0q, int total4) {
  int i = blockIdx.x * blockDim.x + threadIdx.x;
  if (i >= total4) return;
  float a_in = scal[0];
  float4 v = ((const float4*)x0)[i];
  char4 o;
  o.x = (int8_t)rintf(fminf(fmaxf(fdiv(v.x, a_in), -8.f), 7.f));
  o.y = (int8_t)rintf(fminf(fmaxf(fdiv(v.y, a_in), -8.f), 7.f));
  o.z = (int8_t)rintf(fminf(fmaxf(fdiv(v.z, a_in), -8.f), 7.f));
  o.w = (int8_t)rintf(fminf(fmaxf(fdiv(v.w, a_in), -8.f), 7.f));
  ((char4*)x0q)[i] = o;
}

// row-wise 4-bit weight quant: wq = round(clip(w / alpha[row], -8, 7))
__global__ void quant_w_kernel(const float* __restrict__ w,
                               const float* __restrict__ alpha,
                               int8_t* __restrict__ wq, int total) {
  int i = blockIdx.x * blockDim.x + threadIdx.x;
  if (i >= total) return;
  int row = i / CC;
  float t = fminf(fmaxf(fdiv(w[i], alpha[row]), -8.f), 7.f);
  wq[i] = (int8_t)rintf(t);
}

// ---------------------------------------------------------------------------
// GEMM1 (i8 MFMA): 128(seq) x 128(ch) tile, 4 waves, 64x64 quadrant per wave
// (wave w: seq half w&1, ch half w>>1).  Double-buffered staging, 1 barrier
// per K-iter.  q/k blocks: D = W*X^T (lane's C-regs = 4 consecutive ch) ->
// head-phased scaled-LN + 3b quant.  v blocks: D = X*W^T (swapped operands;
// lane's C-regs = 4 consecutive seq) -> packed dword transpose writes.
// 128 cols = 2 full heads per block (col tiles never cross q/k/v sections).
// ---------------------------------------------------------------------------
__global__ __launch_bounds__(256) void gemm_qkv_kernel(
    const int8_t* __restrict__ Aq, const int8_t* __restrict__ Wq,
    const float* __restrict__ biasq, const float* __restrict__ scal,
    const float* __restrict__ qkv_alpha, const float* __restrict__ qparams,
    int8_t* __restrict__ q2, int8_t* __restrict__ k2,
    int8_t* __restrict__ v2t) {
  __shared__ __align__(16) char smem[46080];
  // staging: Abuf[2] @ 0,10240 ; Bbuf[2] @ 20480,30720   (each [128][80] i8)
  // epilogue overlays: XS [128][68] f32 @ 0 ; meanS @34816 ; denS @35328 ;
  //                    Ot [128][80] i8 @ 35840 ; OtV [128][144] i8 @ 0
  float* XS = (float*)smem;                      // stride 68 floats (16B align)
  float* meanS = (float*)(smem + 34816);
  float* denS = (float*)(smem + 35328);
  int8_t* Ot = (int8_t*)(smem + 35840);
  int8_t* OtV = (int8_t*)smem;

  const int g = blockIdx.x, rb = blockIdx.y;
  const int tid = threadIdx.x;
  const int w = tid >> 6, lane = tid & 63, quad = lane >> 4, c16 = lane & 15;
  const int row0 = rb * 128, col0 = g * 128;
  const int sec = g / 6, gg = g % 6;
  const int b_idx = row0 >> 9, nbase = row0 & (NN - 1);
  const int seq0 = 64 * (w & 1), ch0 = 64 * (w >> 1);
  // staging assignment: thread -> 2 rows (r, r+64), 16B column (tid&3)*16
  const int strow = tid >> 2, stcol = (tid & 3) << 4;

  v4i acc[4][4];
#pragma unroll
  for (int i = 0; i < 4; i++)
#pragma unroll
    for (int j = 0; j < 4; j++) acc[i][j] = (v4i){0, 0, 0, 0};

  int4 a0 = *(const int4*)(Aq + (size_t)(row0 + strow) * CC + stcol);
  int4 a1 = *(const int4*)(Aq + (size_t)(row0 + 64 + strow) * CC + stcol);
  int4 b0 = *(const int4*)(Wq + (size_t)(col0 + strow) * CC + stcol);
  int4 b1 = *(const int4*)(Wq + (size_t)(col0 + 64 + strow) * CC + stcol);
  {
    int8_t* Ab = (int8_t*)smem;
    int8_t* Bb = (int8_t*)(smem + 20480);
    *(int4*)(Ab + strow * 80 + stcol) = a0;
    *(int4*)(Ab + (64 + strow) * 80 + stcol) = a1;
    *(int4*)(Bb + strow * 80 + stcol) = b0;
    *(int4*)(Bb + (64 + strow) * 80 + stcol) = b1;
  }

  for (int kt = 0; kt < 12; kt++) {
    __syncthreads();
    const int cur = kt & 1;
    if (kt < 11) {
      int k0 = (kt + 1) * 64;
      a0 = *(const int4*)(Aq + (size_t)(row0 + strow) * CC + k0 + stcol);
      a1 = *(const int4*)(Aq + (size_t)(row0 + 64 + strow) * CC + k0 + stcol);
      b0 = *(const int4*)(Wq + (size_t)(col0 + strow) * CC + k0 + stcol);
      b1 = *(const int4*)(Wq + (size_t)(col0 + 64 + strow) * CC + k0 + stcol);
    }
    const int8_t* Ab = (const int8_t*)(smem + cur * 10240);
    const int8_t* Bb = (const int8_t*)(smem + 20480 + cur * 10240);
    v4i xf[4], wf[4];
#pragma unroll
    for (int i = 0; i < 4; i++)
      xf[i] = *(const v4i*)(Ab + (seq0 + 16 * i + c16) * 80 + quad * 16);
#pragma unroll
    for (int i = 0; i < 4; i++)
      wf[i] = *(const v4i*)(Bb + (ch0 + 16 * i + c16) * 80 + quad * 16);
    if (sec < 2) {
#pragma unroll
      for (int sm = 0; sm < 4; sm++)
#pragma unroll
        for (int sn = 0; sn < 4; sn++)
          acc[sm][sn] = __builtin_amdgcn_mfma_i32_16x16x64_i8(wf[sm], xf[sn],
                                                              acc[sm][sn], 0, 0, 0);
    } else {
#pragma unroll
      for (int sm = 0; sm < 4; sm++)
#pragma unroll
        for (int sn = 0; sn < 4; sn++)
          acc[sm][sn] = __builtin_amdgcn_mfma_i32_16x16x64_i8(xf[sn], wf[sm],
                                                              acc[sm][sn], 0, 0, 0);
    }
    if (kt < 11) {
      int8_t* An = (int8_t*)(smem + (cur ^ 1) * 10240);
      int8_t* Bn = (int8_t*)(smem + 20480 + (cur ^ 1) * 10240);
      *(int4*)(An + strow * 80 + stcol) = a0;
      *(int4*)(An + (64 + strow) * 80 + stcol) = a1;
      *(int4*)(Bn + strow * 80 + stcol) = b0;
      *(int4*)(Bn + (64 + strow) * 80 + stcol) = b1;
    }
  }

  if (sec == 2) {
    // ---- V path: 3b quant, lane's r-dim = consecutive seq -> dword writes
    __syncthreads();  // staging dead; OtV overlay safe
    const float a_in = scal[0], vact = scal[3];
#pragma unroll
    for (int sm = 0; sm < 4; sm++) {
      int chg = ch0 + 16 * sm + c16;          // block-local channel 0..127
      int colf = col0 + chg;
      float bq = biasq[colf];
      float va = fdiv(vact, fmul(a_in, qkv_alpha[colf]));
#pragma unroll
      for (int sn = 0; sn < 4; sn++) {
        int seqq = seq0 + 16 * sn + 4 * quad;  // r consecutive seq
        uint32_t pack = 0;
#pragma unroll
        for (int r = 0; r < 4; r++) {
          float vint = fadd((float)acc[sm][sn][r], bq);
          float t = fminf(fmaxf(fdiv(vint, va), -4.f), 3.f);
          pack |= ((uint32_t)(uint8_t)(int8_t)rintf(t)) << (8 * r);
        }
        *(uint32_t*)(OtV + chg * 144 + seqq) = pack;
      }
    }
    __syncthreads();
#pragma unroll
    for (int c = 0; c < 4; c++) {
      int id = tid + 256 * c;
      int rowx = id >> 3, off = (id & 7) << 4;
      int head = rowx >> 6, d = rowx & 63;
      size_t bhh = (size_t)b_idx * HH + 2 * gg + head;
      int4 ov = *(const int4*)(OtV + rowx * 144 + off);
      *(int4*)(v2t + (bhh * HD + d) * NN + nbase + off) = ov;
    }
  } else {
    // ---- q/k path: head-phased scaled LN + 3b quant
    const float* ap = qparams + (sec == 0 ? 0 : 128);
    int8_t* dst = (sec == 0) ? q2 : k2;
    const int own_half = w >> 1;
    for (int hp = 0; hp < 2; hp++) {
      __syncthreads();  // staging / previous phase dead
      if (own_half == hp) {
#pragma unroll
        for (int sm = 0; sm < 4; sm++) {
          int chq = 16 * sm + 4 * quad;        // channel-in-head (r base)
          int colf = col0 + 64 * hp + chq;
          float4 bq = *(const float4*)(biasq + colf);
          float4 al = *(const float4*)(qkv_alpha + colf);
          const float* bqp = (const float*)&bq;
          const float* alp = (const float*)&al;
#pragma unroll
          for (int sn = 0; sn < 4; sn++) {
            int seq = seq0 + 16 * sn + c16;
            float4 xv;
            float* xp = (float*)&xv;
#pragma unroll
            for (int r = 0; r < 4; r++)
              xp[r] = fmul(fadd((float)acc[sm][sn][r], bqp[r]), alp[r]);
            *(float4*)(XS + seq * 68 + chq) = xv;
          }
        }
      }
      __syncthreads();
      if (tid < 128) np_stats_64_v4(XS + tid * 68, &meanS[tid], &denS[tid]);
      __syncthreads();
      if (own_half == hp) {
#pragma unroll
        for (int sm = 0; sm < 4; sm++) {
          int chq = 16 * sm + 4 * quad;
          float4 apa = *(const float4*)(ap + chq);
          float4 apb = *(const float4*)(ap + 64 + chq);
          const float* apap = (const float*)&apa;
          const float* apbp = (const float*)&apb;
#pragma unroll
          for (int sn = 0; sn < 4; sn++) {
            int seq = seq0 + 16 * sn + c16;
            float4 xv = *(const float4*)(XS + seq * 68 + chq);
            const float* xp = (const float*)&xv;
            float mean = meanS[seq], den = denS[seq];
            uint32_t pack = 0;
#pragma unroll
            for (int r = 0; r < 4; r++) {
              float xn = fdiv(fsub(xp[r], mean), den);
              float t = fdiv(fadd(xn, apbp[r]), apap[r]);
              t = fminf(fmaxf(t, -4.f), 3.f);
              pack |= ((uint32_t)(uint8_t)(int8_t)rintf(t)) << (8 * r);
            }
            *(uint32_t*)(Ot + seq * 80 + chq) = pack;
          }
        }
      }
      __syncthreads();
      {
        size_t bhh = (size_t)b_idx * HH + 2 * gg + hp;
#pragma unroll
        for (int c = 0; c < 2; c++) {
          int id = tid + 256 * c;
          int rowx = id >> 2, off = (id & 3) << 4;
          int4 ov = *(const int4*)(Ot + rowx * 80 + off);
          *(int4*)(dst + (bhh * NN + nbase + rowx) * HD + off) = ov;
        }
      }
    }
  }
}

// ---------------------------------------------------------------------------
// Attention (i8 MFMA), per (qtile64, b*h).  QK^T computed transposed
// (D2 = K_sub·Q^T).  Pass A: m kept packed in registers; row sum of 2^m
// exact in any order -> shuffle reduce.  Pass B: weight = rint(min(ldexp(u,m),7))
// with u = (1/S)/attnm hoisted per row (pow2 scaling commutes with RN).
// ---------------------------------------------------------------------------
__global__ __launch_bounds__(256) void attn_kernel(
    const int8_t* __restrict__ q2, const int8_t* __restrict__ k2,
    const int8_t* __restrict__ v2t, const float* __restrict__ scal,
    int8_t* __restrict__ x1q) {
  __shared__ __align__(16) int8_t Qs[64][80];
  __shared__ __align__(16) int8_t Ks[64][80];  // K tiles pass A; Xt epilogue
  __shared__ __align__(16) int8_t Vt[64][80];
  __shared__ __align__(16) int8_t At[64][80];

  const int qt = blockIdx.x, bh = blockIdx.y;
  const int tid = threadIdx.x;
  const int w = tid >> 6, lane = tid & 63, quad = lane >> 4, c16 = lane & 15;
  const int sr = tid >> 2, scol = (tid & 3) << 4;
  const float attnm = scal[4];
  const float coef =
      fmul(1.4426950408889634f, fmul(fmul(0.125f, scal[1]), scal[2]));
  const float coef128 = fmul(coef, 128.f);  // exact pow2 scale
  const size_t base = (size_t)bh * NN * HD;

  *(int4*)&Qs[sr][scol] =
      *(const int4*)(q2 + base + (size_t)(qt * 64 + sr) * HD + scol);
  __syncthreads();
  v4i qf = *(const v4i*)&Qs[16 * w + c16][quad * 16];

  // ---- pass A: QK^T, m -> registers, row sums of 2^m ----
  uint32_t mpack[8][4];
  float Srow = 0.f;
  int4 kv = *(const int4*)(k2 + base + (size_t)sr * HD + scol);
#pragma unroll
  for (int kt = 0; kt < 8; kt++) {
    *(int4*)&Ks[sr][scol] = kv;
    __syncthreads();
    if (kt < 7)
      kv = *(const int4*)(k2 + base + (size_t)((kt + 1) * 64 + sr) * HD + scol);
    float psum = 0.f;
#pragma unroll
    for (int f = 0; f < 4; f++) {
      v4i kf = *(const v4i*)&Ks[16 * f + c16][quad * 16];
      v4i d2 = (v4i){0, 0, 0, 0};
      d2 = __builtin_amdgcn_mfma_i32_16x16x64_i8(kf, qf, d2, 0, 0, 0);
      uint32_t pk = 0;
#pragma unroll
      for (int r = 0; r < 4; r++) {
        float e = truncf(fmul(coef128, (float)d2[r]));
        int mi = (int)rintf(fmul(e, 0.0078125f));
        psum = fadd(psum, ldexpf(1.0f, mi));
        pk |= ((uint32_t)(uint8_t)(int8_t)mi) << (8 * r);
      }
      mpack[kt][f] = pk;
    }
    psum = fadd(psum, __shfl_xor(psum, 16, 64));
    psum = fadd(psum, __shfl_xor(psum, 32, 64));
    Srow = fadd(Srow, psum);
    __syncthreads();
  }
  const float u = fdiv(fdiv(1.0f, Srow), attnm);  // per-row, hoisted divides

  // ---- pass B: requantize from register m, AV ----
  v4i xacc[4];
#pragma unroll
  for (int s = 0; s < 4; s++) xacc[s] = (v4i){0, 0, 0, 0};

  int4 vv = *(const int4*)(v2t + ((size_t)bh * HD + sr) * NN + scol);
#pragma unroll
  for (int kt = 0; kt < 8; kt++) {
    *(int4*)&Vt[sr][scol] = vv;
    __syncthreads();
    if (kt < 7)
      vv = *(const int4*)(v2t + ((size_t)bh * HD + sr) * NN + (kt + 1) * 64 +
                          scol);
#pragma unroll
    for (int f = 0; f < 4; f++) {
      uint32_t pk = mpack[kt][f];
      uint32_t wpk = 0;
#pragma unroll
      for (int r = 0; r < 4; r++) {
        int mi = (int)(int8_t)(pk >> (8 * r));
        float t = fminf(ldexpf(u, mi), 7.f);  // >0 so low clip never binds
        wpk |= ((uint32_t)(uint8_t)(int8_t)rintf(t)) << (8 * r);
      }
      *(uint32_t*)&At[16 * w + c16][16 * f + 4 * quad] = wpk;
    }
    // At rows are wave-private: only need LDS drain, not a full barrier
    asm volatile("s_waitcnt lgkmcnt(0)" ::: "memory");
    v4i af = *(const v4i*)&At[16 * w + c16][quad * 16];
#pragma unroll
    for (int s = 0; s < 4; s++) {
      v4i vf = *(const v4i*)&Vt[16 * s + c16][quad * 16];
      xacc[s] = __builtin_amdgcn_mfma_i32_16x16x64_i8(vf, af, xacc[s], 0, 0, 0);
    }
    __syncthreads();
  }

  // epilogue: x1_q = round(clip(x1/pa, -4, 3)) -> [B,H,N,hd] int8 (Xt := Ks)
  const float pa = fdiv(scal[5], fmul(attnm, scal[3]));
#pragma unroll
  for (int s = 0; s < 4; s++) {
    uint32_t pack = 0;
#pragma unroll
    for (int r = 0; r < 4; r++) {
      float t = fminf(fmaxf(fdiv((float)xacc[s][r], pa), -4.f), 3.f);
      pack |= ((uint32_t)(uint8_t)(int8_t)rintf(t)) << (8 * r);
    }
    *(uint32_t*)&Ks[16 * w + c16][16 * s + 4 * quad] = pack;
  }
  __syncthreads();
  int4 ov = *(const int4*)&Ks[sr][scol];
  *(int4*)(x1q + ((size_t)bh * NN + qt * 64 + sr) * HD + scol) = ov;
}

// ---------------------------------------------------------------------------
// GEMM2 (i8 MFMA): 128x128 tile, 64x64/wave, double-buffered.  D = W*X^T;
// out = acc * proj_alpha * pact_m + proj_bias, float4 stores.
// x1q is [B,H,N,hd]; K-tile kt == head kt -> contiguous 64B rows.
// ---------------------------------------------------------------------------
__global__ __launch_bounds__(256) void gemm_proj_kernel(
    const int8_t* __restrict__ x1q, const int8_t* __restrict__ Wq,
    const float* __restrict__ proj_alpha, const float* __restrict__ proj_bias,
    const float* __restrict__ scal, float* __restrict__ out) {
  __shared__ __align__(16) char smem[40960];  // Abuf[2]@0,10240 Bbuf[2]@20480,30720
  const int g = blockIdx.x, rb = blockIdx.y;
  const int tid = threadIdx.x;
  const int w = tid >> 6, lane = tid & 63, quad = lane >> 4, c16 = lane & 15;
  const int row0 = rb * 128, col0 = g * 128;
  const int b_idx = row0 >> 9, nbase = row0 & (NN - 1);
  const int seq0 = 64 * (w & 1), ch0 = 64 * (w >> 1);
  const int strow = tid >> 2, stcol = (tid & 3) << 4;

  v4i acc[4][4];
#pragma unroll
  for (int i = 0; i < 4; i++)
#pragma unroll
    for (int j = 0; j < 4; j++) acc[i][j] = (v4i){0, 0, 0, 0};

  int4 a0 = *(const int4*)(
      x1q + (((size_t)b_idx * HH) * NN + nbase + strow) * HD + stcol);
  int4 a1 = *(const int4*)(
      x1q + (((size_t)b_idx * HH) * NN + nbase + 64 + strow) * HD + stcol);
  int4 b0 = *(const int4*)(Wq + (size_t)(col0 + strow) * CC + stcol);
  int4 b1 = *(const int4*)(Wq + (size_t)(col0 + 64 + strow) * CC + stcol);
  {
    int8_t* Ab = (int8_t*)smem;
    int8_t* Bb = (int8_t*)(smem + 20480);
    *(int4*)(Ab + strow * 80 + stcol) = a0;
    *(int4*)(Ab + (64 + strow) * 80 + stcol) = a1;
    *(int4*)(Bb + strow * 80 + stcol) = b0;
    *(int4*)(Bb + (64 + strow) * 80 + stcol) = b1;
  }

  for (int kt = 0; kt < 12; kt++) {
    __syncthreads();
    const int cur = kt & 1;
    if (kt < 11) {
      a0 = *(const int4*)(
          x1q + (((size_t)b_idx * HH + kt + 1) * NN + nbase + strow) * HD +
          stcol);
      a1 = *(const int4*)(
          x1q + (((size_t)b_idx * HH + kt + 1) * NN + nbase + 64 + strow) * HD +
          stcol);
      b0 = *(const int4*)(Wq + (size_t)(col0 + strow) * CC + (kt + 1) * 64 +
                          stcol);
      b1 = *(const int4*)(Wq + (size_t)(col0 + 64 + strow) * CC +
                          (kt + 1) * 64 + stcol);
    }
    const int8_t* Ab = (const int8_t*)(smem + cur * 10240);
    const int8_t* Bb = (const int8_t*)(smem + 20480 + cur * 10240);
    v4i xf[4], wf[4];
#pragma unroll
    for (int i = 0; i < 4; i++)
      xf[i] = *(const v4i*)(Ab + (seq0 + 16 * i + c16) * 80 + quad * 16);
#pragma unroll
    for (int i = 0; i < 4; i++)
      wf[i] = *(const v4i*)(Bb + (ch0 + 16 * i + c16) * 80 + quad * 16);
#pragma unroll
    for (int sm = 0; sm < 4; sm++)
#pragma unroll
      for (int sn = 0; sn < 4; sn++)
        acc[sm][sn] = __builtin_amdgcn_mfma_i32_16x16x64_i8(wf[sm], xf[sn],
                                                            acc[sm][sn], 0, 0, 0);
    if (kt < 11) {
      int8_t* An = (int8_t*)(smem + (cur ^ 1) * 10240);
      int8_t* Bn = (int8_t*)(smem + 20480 + (cur ^ 1) * 10240);
      *(int4*)(An + strow * 80 + stcol) = a0;
      *(int4*)(An + (64 + strow) * 80 + stcol) = a1;
      *(int4*)(Bn + strow * 80 + stcol) = b0;
      *(int4*)(Bn + (64 + strow) * 80 + stcol) = b1;
    }
  }

  const float pact = scal[5];
#pragma unroll
  for (int sm = 0; sm < 4; sm++) {
    int colb = col0 + ch0 + 16 * sm + 4 * quad;
    float4 al = *(const float4*)(proj_alpha + colb);
    float4 bi = *(const float4*)(proj_bias + colb);
    const float* alp = (const float*)&al;
    const float* bip = (const float*)&bi;
#pragma unroll
    for (int sn = 0; sn < 4; sn++) {
      int m = row0 + seq0 + 16 * sn + c16;
      float4 o;
      float* op = (float*)&o;
#pragma unroll
      for (int r = 0; r < 4; r++)
        op[r] = fadd(fmul(fmul((float)acc[sm][sn][r], alp[r]), pact), bip[r]);
      *(float4*)(out + (size_t)m * CC + colb) = o;
    }
  }
}

extern "C" void kernel_launch(void* const* d_in, const int* in_sizes, int n_in,
                              void* d_out, int out_size, void* d_ws,
                              size_t ws_size, hipStream_t stream) {
  const float* x0 = (const float*)d_in[0];
  const float* qkv_w = (const float*)d_in[1];
  const float* qkv_alpha = (const float*)d_in[2];
  const float* qkv_bias = (const float*)d_in[3];
  const float* qkv_act_alpha = (const float*)d_in[4];
  const float* proj_w = (const float*)d_in[5];
  const float* proj_alpha = (const float*)d_in[6];
  const float* proj_bias = (const float*)d_in[7];
  const float* proj_act_alpha = (const float*)d_in[8];
  const float* normq_w = (const float*)d_in[9];
  const float* normq_b = (const float*)d_in[10];
  const float* normk_w = (const float*)d_in[11];
  const float* normk_b = (const float*)d_in[12];
  const float* qact_alpha = (const float*)d_in[13];
  const float* kact_alpha = (const float*)d_in[14];
  const float* vact_alpha = (const float*)d_in[15];
  const float* attnact_alpha = (const float*)d_in[16];

  char* ws = (char*)d_ws;
  size_t off = 0;
  auto alloc = [&](size_t bytes) -> char* {
    char* p = ws + off;
    off += (bytes + 255) & ~(size_t)255;
    return p;
  };
  float* scal = (float*)alloc(64 * 4);
  float* qparams = (float*)alloc(256 * 4);
  float* biasq = (float*)alloc(QKV_C * 4);
  int8_t* x0q = (int8_t*)alloc((size_t)M_ROWS * CC);
  int8_t* wq = (int8_t*)alloc((size_t)QKV_C * CC);
  int8_t* pwq = (int8_t*)alloc((size_t)CC * CC);
  int8_t* q2 = (int8_t*)alloc((size_t)BB * HH * NN * HD);
  int8_t* k2 = (int8_t*)alloc((size_t)BB * HH * NN * HD);
  int8_t* v2t = (int8_t*)alloc((size_t)BB * HH * NN * HD);
  int8_t* x1q = (int8_t*)alloc((size_t)M_ROWS * CC);

  prep_kernel<<<1, 256, 0, stream>>>(qkv_act_alpha, proj_act_alpha, qact_alpha,
                                     kact_alpha, vact_alpha, attnact_alpha,
                                     normq_w, normq_b, normk_w, normk_b,
                                     qkv_bias, qkv_alpha, scal, qparams, biasq);

  int total4 = M_ROWS * CC / 4;
  quant_x0_kernel<<<(total4 + 255) / 256, 256, 0, stream>>>(x0, scal, x0q,
                                                            total4);
  quant_w_kernel<<<(QKV_C * CC + 255) / 256, 256, 0, stream>>>(
      qkv_w, qkv_alpha, wq, QKV_C * CC);
  quant_w_kernel<<<(CC * CC + 255) / 256, 256, 0, stream>>>(proj_w, proj_alpha,
                                                            pwq, CC * CC);

  gemm_qkv_kernel<<<dim3(QKV_C / 128, M_ROWS / 128), 256, 0, stream>>>(
      x0q, wq, biasq, scal, qkv_alpha, qparams, q2, k2, v2t);

  attn_kernel<<<dim3(NN / 64, BB * HH), 256, 0, stream>>>(q2, k2, v2t, scal,
                                                          x1q);

  gemm_proj_kernel<<<dim3(CC / 128, M_ROWS / 128), 256, 0, stream>>>(
      x1q, pwq, proj_alpha, proj_bias, scal, (float*)d_out);
}

// Round 5
// 361.989 us; speedup vs baseline: 6.7478x; 1.0250x over previous
//
#include <hip/hip_runtime.h>
#include <stdint.h>

// ---------------------------------------------------------------------------
// Q_Attention: quantized ViT attention block, bit-faithful to the JAX/numpy ref.
// B=32, N=512, C=768, H=12, hd=64.  All GEMMs on i8 MFMA (int32 acc, exact).
// R5: barrier-free LDS-free GEMMs.  Inputs re-tiled [kt][row][64] so every
// 32x32x32_i8 MFMA fragment is one coalesced 1024B global load (L1/L2-hot).
// Wave = independent 64x64 output tile; LayerNorm fully in registers (the
// 32x32 C-layout splits a 64-ch row exactly along numpy's 8-acc boundaries;
// lane-pair combine via shfl_xor(32), exact by IEEE add commutativity).
// LDS only as wave-private 5KB output-pack tiles (lgkmcnt, no barriers).
// ---------------------------------------------------------------------------

#define BB 32
#define NN 512
#define CC 768
#define HH 12
#define HD 64
#define M_ROWS (BB * NN)     // 16384
#define QKV_C (3 * CC)       // 2304
#define KTA ((size_t)M_ROWS * 64)   // x0q kt-slice stride
#define KTB ((size_t)QKV_C * 64)    // wq  kt-slice stride
#define KTP ((size_t)CC * 64)       // pwq kt-slice stride

typedef int v4i __attribute__((ext_vector_type(4)));
typedef int v16i __attribute__((ext_vector_type(16)));

__device__ __forceinline__ float fadd(float a, float b) { return __fadd_rn(a, b); }
__device__ __forceinline__ float fmul(float a, float b) { return __fmul_rn(a, b); }
__device__ __forceinline__ float fdiv(float a, float b) { return __fdiv_rn(a, b); }
__device__ __forceinline__ float fsub(float a, float b) { return __fsub_rn(a, b); }

// numpy pairwise_sum, n=96 (no remainder): 8 accumulators, then pairwise combine
__device__ float np_sum_96(const float* a) {
  float r[8];
#pragma unroll
  for (int j = 0; j < 8; j++) r[j] = a[j];
  for (int i = 8; i < 96; i += 8)
#pragma unroll
    for (int j = 0; j < 8; j++) r[j] = fadd(r[j], a[i + j]);
  return fadd(fadd(fadd(r[0], r[1]), fadd(r[2], r[3])),
              fadd(fadd(r[4], r[5]), fadd(r[6], r[7])));
}

// numpy pairwise mean of 12: 8-acc combine + 4 sequential remainder adds
__device__ float np_mean_12(const float* a) {
  float r[8];
#pragma unroll
  for (int j = 0; j < 8; j++) r[j] = a[j];
  float res = fadd(fadd(fadd(r[0], r[1]), fadd(r[2], r[3])),
                   fadd(fadd(r[4], r[5]), fadd(r[6], r[7])));
  res = fadd(res, a[8]);
  res = fadd(res, a[9]);
  res = fadd(res, a[10]);
  res = fadd(res, a[11]);
  return fdiv(res, 12.0f);
}

// ---------------------------------------------------------------------------
// prep: scalar means + folded LN quant params + integer qkv bias
// scal: [0]=a_in [1]=qact_m [2]=kact_m [3]=vact_m [4]=attnact_m [5]=pact_m
// qparams: [0:64]=qalpha [64:128]=qbias [128:192]=kalpha [192:256]=kbias
// ---------------------------------------------------------------------------
__global__ void prep_kernel(const float* __restrict__ qkv_act_alpha,
                            const float* __restrict__ proj_act_alpha,
                            const float* __restrict__ qact_alpha,
                            const float* __restrict__ kact_alpha,
                            const float* __restrict__ vact_alpha,
                            const float* __restrict__ attnact_alpha,
                            const float* __restrict__ normq_w,
                            const float* __restrict__ normq_b,
                            const float* __restrict__ normk_w,
                            const float* __restrict__ normk_b,
                            const float* __restrict__ qkv_bias,
                            const float* __restrict__ qkv_alpha,
                            float* __restrict__ scal,
                            float* __restrict__ qparams,
                            float* __restrict__ biasq) {
  __shared__ float s_scal[8];
  __shared__ float chunk[16];
  int tid = threadIdx.x;
  if (tid < 8) chunk[tid] = np_sum_96(qkv_act_alpha + 96 * tid);
  else if (tid < 16) chunk[tid] = np_sum_96(proj_act_alpha + 96 * (tid - 8));
  if (tid == 16) s_scal[1] = np_mean_12(qact_alpha);
  if (tid == 17) s_scal[2] = np_mean_12(kact_alpha);
  if (tid == 18) s_scal[3] = np_mean_12(vact_alpha);
  if (tid == 19) s_scal[4] = np_mean_12(attnact_alpha);
  __syncthreads();
  if (tid == 0) {
    float s0 = fadd(fadd(chunk[0], chunk[1]), fadd(chunk[2], chunk[3]));
    float s1 = fadd(fadd(chunk[4], chunk[5]), fadd(chunk[6], chunk[7]));
    s_scal[0] = fdiv(fadd(s0, s1), 768.0f);
    float p0 = fadd(fadd(chunk[8], chunk[9]), fadd(chunk[10], chunk[11]));
    float p1 = fadd(fadd(chunk[12], chunk[13]), fadd(chunk[14], chunk[15]));
    s_scal[5] = fdiv(fadd(p0, p1), 768.0f);
  }
  __syncthreads();
  if (tid < 6) scal[tid] = s_scal[tid];
  if (tid < 64) {
    qparams[tid]       = fdiv(s_scal[1], normq_w[tid]);    // act_a / nw
    qparams[64 + tid]  = fdiv(normq_b[tid], normq_w[tid]); // nb / nw
    qparams[128 + tid] = fdiv(s_scal[2], normk_w[tid]);
    qparams[192 + tid] = fdiv(normk_b[tid], normk_w[tid]);
  }
  float a_in = s_scal[0];
  for (int c = tid; c < QKV_C; c += blockDim.x)
    biasq[c] = truncf(fdiv(fdiv(qkv_bias[c], a_in), qkv_alpha[c]));
}

// x0_q = round(clip(x0 / a_in, -8, 7)) -> int8, K-TILED layout [12][16384][64]
__global__ void quant_x0_kernel(const float* __restrict__ x0,
                                const float* __restrict__ scal,
                                int8_t* __restrict__ x0q, int total4) {
  int i = blockIdx.x * blockDim.x + threadIdx.x;
  if (i >= total4) return;
  float a_in = scal[0];
  float4 v = ((const float4*)x0)[i];
  char4 o;
  o.x = (int8_t)rintf(fminf(fmaxf(fdiv(v.x, a_in), -8.f), 7.f));
  o.y = (int8_t)rintf(fminf(fmaxf(fdiv(v.y, a_in), -8.f), 7.f));
  o.z = (int8_t)rintf(fminf(fmaxf(fdiv(v.z, a_in), -8.f), 7.f));
  o.w = (int8_t)rintf(fminf(fmaxf(fdiv(v.w, a_in), -8.f), 7.f));
  int seq = i / 192;
  int kp = (i - seq * 192) * 4;
  *(char4*)(x0q + ((size_t)(kp >> 6) * M_ROWS + seq) * 64 + (kp & 63)) = o;
}

// row-wise 4-bit weight quant -> K-TILED layout [CC/64][rows][64]
__global__ void quant_w_kernel(const float* __restrict__ w,
                               const float* __restrict__ alpha,
                               int8_t* __restrict__ wq, int rows, int total) {
  int i = blockIdx.x * blockDim.x + threadIdx.x;
  if (i >= total) return;
  int row = i / CC;
  int k = i - row * CC;
  float t = fminf(fmaxf(fdiv(w[i], alpha[row]), -8.f), 7.f);
  wq[((size_t)(k >> 6) * rows + row) * 64 + (k & 63)] =
      (int8_t)rintf(t);
}

// ---------------------------------------------------------------------------
// GEMM1 (i8 MFMA 32x32x32): barrier-free.  Block = 256seq x 64ch (one head of
// one of q/k/v); 4 independent waves each own 64seq x 64ch (2x2 of 32x32).
// Fragments loaded straight from global ([kt][row][64] tiling -> coalesced).
// q/k: D = W*X^T; LN fully in registers (numpy 8-acc order preserved);
// v: D = X*W^T (swapped operands) so transpose packs into dwords.
// Wave-private LDS pack tile -> coalesced int4 stores.  No __syncthreads.
// ---------------------------------------------------------------------------
__global__ __launch_bounds__(256, 4) void gemm_qkv_kernel(
    const int8_t* __restrict__ Aq, const int8_t* __restrict__ Wq,
    const float* __restrict__ biasq, const float* __restrict__ scal,
    const float* __restrict__ qkv_alpha, const float* __restrict__ qparams,
    int8_t* __restrict__ q2, int8_t* __restrict__ k2,
    int8_t* __restrict__ v2t) {
  __shared__ __align__(16) int8_t packT[4][5120];  // [wave][64 rows x 80]

  const int g = blockIdx.x, rb = blockIdx.y;
  const int tid = threadIdx.x;
  const int w = tid >> 6, lane = tid & 63;
  const int l31 = lane & 31, hi = lane >> 5;
  const int sec = g / HH, head = g % HH;
  const int col0 = g * 64;
  const int b_idx = rb >> 1, nbase = (rb & 1) * 256;
  const int w64 = w * 64;
  const size_t bh = (size_t)b_idx * HH + head;

  v16i acc[2][2];
#pragma unroll
  for (int i = 0; i < 2; i++)
#pragma unroll
    for (int j = 0; j < 2; j++) acc[i][j] = (v16i)(0);

  const int8_t* pa0 = Aq + ((size_t)(rb * 256 + w64 + l31)) * 64 + hi * 16;
  const int8_t* pa1 = pa0 + 32 * 64;
  const int8_t* pb0 = Wq + ((size_t)(col0 + l31)) * 64 + hi * 16;
  const int8_t* pb1 = pb0 + 32 * 64;

  if (sec < 2) {  // q/k: D = W * X^T
#pragma unroll
    for (int kt = 0; kt < 12; kt++) {
      v4i A0a = *(const v4i*)(pa0 + kt * KTA);
      v4i A1a = *(const v4i*)(pa1 + kt * KTA);
      v4i B0a = *(const v4i*)(pb0 + kt * KTB);
      v4i B1a = *(const v4i*)(pb1 + kt * KTB);
      v4i A0b = *(const v4i*)(pa0 + kt * KTA + 32);
      v4i A1b = *(const v4i*)(pa1 + kt * KTA + 32);
      v4i B0b = *(const v4i*)(pb0 + kt * KTB + 32);
      v4i B1b = *(const v4i*)(pb1 + kt * KTB + 32);
      acc[0][0] = __builtin_amdgcn_mfma_i32_32x32x32_i8(B0a, A0a, acc[0][0], 0, 0, 0);
      acc[0][1] = __builtin_amdgcn_mfma_i32_32x32x32_i8(B0a, A1a, acc[0][1], 0, 0, 0);
      acc[1][0] = __builtin_amdgcn_mfma_i32_32x32x32_i8(B1a, A0a, acc[1][0], 0, 0, 0);
      acc[1][1] = __builtin_amdgcn_mfma_i32_32x32x32_i8(B1a, A1a, acc[1][1], 0, 0, 0);
      acc[0][0] = __builtin_amdgcn_mfma_i32_32x32x32_i8(B0b, A0b, acc[0][0], 0, 0, 0);
      acc[0][1] = __builtin_amdgcn_mfma_i32_32x32x32_i8(B0b, A1b, acc[0][1], 0, 0, 0);
      acc[1][0] = __builtin_amdgcn_mfma_i32_32x32x32_i8(B1b, A0b, acc[1][0], 0, 0, 0);
      acc[1][1] = __builtin_amdgcn_mfma_i32_32x32x32_i8(B1b, A1b, acc[1][1], 0, 0, 0);
    }
    // ---- epilogue: x = (acc + biasq)*alpha; register LN; 3b quant ----
    // acc[i][j][r]: ch = col0 + 32i + 8(r>>2) + 4hi + (r&3), seq = 32j + l31
    float xs[2][2][16];
#pragma unroll
    for (int i = 0; i < 2; i++)
#pragma unroll
      for (int b = 0; b < 4; b++) {
        int cg = col0 + 32 * i + 8 * b + 4 * hi;
        float4 bqv = *(const float4*)(biasq + cg);
        float4 alv = *(const float4*)(qkv_alpha + cg);
        const float* bqp = (const float*)&bqv;
        const float* alp = (const float*)&alv;
#pragma unroll
        for (int j = 0; j < 2; j++)
#pragma unroll
          for (int c = 0; c < 4; c++)
            xs[i][j][4 * b + c] =
                fmul(fadd((float)acc[i][j][4 * b + c], bqp[c]), alp[c]);
      }
    // numpy-order stats: acc index = ch&7 = 4hi+c (lane-local!), t = ch>>3 = 4i+b
    float mean[2], den[2];
#pragma unroll
    for (int j = 0; j < 2; j++) {
      float rc[4];
#pragma unroll
      for (int c = 0; c < 4; c++) rc[c] = xs[0][j][c];
#pragma unroll
      for (int b = 1; b < 4; b++)
#pragma unroll
        for (int c = 0; c < 4; c++) rc[c] = fadd(rc[c], xs[0][j][4 * b + c]);
#pragma unroll
      for (int b = 0; b < 4; b++)
#pragma unroll
        for (int c = 0; c < 4; c++) rc[c] = fadd(rc[c], xs[1][j][4 * b + c]);
      float L = fadd(fadd(rc[0], rc[1]), fadd(rc[2], rc[3]));
      float R = __shfl_xor(L, 32, 64);
      float mn = fdiv(fadd(L, R), 64.0f);  // fadd commutative -> both lanes equal
      float vc[4];
#pragma unroll
      for (int c = 0; c < 4; c++) {
        float d = fsub(xs[0][j][c], mn);
        vc[c] = fmul(d, d);
      }
#pragma unroll
      for (int b = 1; b < 4; b++)
#pragma unroll
        for (int c = 0; c < 4; c++) {
          float d = fsub(xs[0][j][4 * b + c], mn);
          vc[c] = fadd(vc[c], fmul(d, d));
        }
#pragma unroll
      for (int b = 0; b < 4; b++)
#pragma unroll
        for (int c = 0; c < 4; c++) {
          float d = fsub(xs[1][j][4 * b + c], mn);
          vc[c] = fadd(vc[c], fmul(d, d));
        }
      float Lv = fadd(fadd(vc[0], vc[1]), fadd(vc[2], vc[3]));
      float Rv = __shfl_xor(Lv, 32, 64);
      float var = fdiv(fadd(Lv, Rv), 63.0f);
      mean[j] = mn;
      den[j] = fadd(__fsqrt_rn(var), 1e-5f);
    }
    const float* ap = qparams + (sec == 0 ? 0 : 128);
#pragma unroll
    for (int i = 0; i < 2; i++)
#pragma unroll
      for (int b = 0; b < 4; b++) {
        int cin = 32 * i + 8 * b + 4 * hi;  // channel-in-head
        float4 a4 = *(const float4*)(ap + cin);
        float4 b4 = *(const float4*)(ap + 64 + cin);
        const float* a4p = (const float*)&a4;
        const float* b4p = (const float*)&b4;
#pragma unroll
        for (int j = 0; j < 2; j++) {
          uint32_t pk = 0;
#pragma unroll
          for (int c = 0; c < 4; c++) {
            float xn = fdiv(fsub(xs[i][j][4 * b + c], mean[j]), den[j]);
            float t = fdiv(fadd(xn, b4p[c]), a4p[c]);
            t = fminf(fmaxf(t, -4.f), 3.f);
            pk |= ((uint32_t)(uint8_t)(int8_t)rintf(t)) << (8 * c);
          }
          *(uint32_t*)&packT[w][(32 * j + l31) * 80 + cin] = pk;
        }
      }
    asm volatile("s_waitcnt lgkmcnt(0)" ::: "memory");
    int8_t* dst = (sec == 0) ? q2 : k2;
    size_t rowbase = bh * NN + nbase + w64;
#pragma unroll
    for (int c = 0; c < 4; c++) {
      int row = 16 * c + (lane >> 2), off = (lane & 3) * 16;
      int4 ov = *(const int4*)&packT[w][row * 80 + off];
      *(int4*)(dst + (rowbase + row) * 64 + off) = ov;
    }
  } else {  // v: D = X * W^T (row = seq -> dword-packed transpose)
#pragma unroll
    for (int kt = 0; kt < 12; kt++) {
      v4i A0a = *(const v4i*)(pa0 + kt * KTA);
      v4i A1a = *(const v4i*)(pa1 + kt * KTA);
      v4i B0a = *(const v4i*)(pb0 + kt * KTB);
      v4i B1a = *(const v4i*)(pb1 + kt * KTB);
      v4i A0b = *(const v4i*)(pa0 + kt * KTA + 32);
      v4i A1b = *(const v4i*)(pa1 + kt * KTA + 32);
      v4i B0b = *(const v4i*)(pb0 + kt * KTB + 32);
      v4i B1b = *(const v4i*)(pb1 + kt * KTB + 32);
      // acc[si][sj]: si = seq block, sj = ch block
      acc[0][0] = __builtin_amdgcn_mfma_i32_32x32x32_i8(A0a, B0a, acc[0][0], 0, 0, 0);
      acc[0][1] = __builtin_amdgcn_mfma_i32_32x32x32_i8(A0a, B1a, acc[0][1], 0, 0, 0);
      acc[1][0] = __builtin_amdgcn_mfma_i32_32x32x32_i8(A1a, B0a, acc[1][0], 0, 0, 0);
      acc[1][1] = __builtin_amdgcn_mfma_i32_32x32x32_i8(A1a, B1a, acc[1][1], 0, 0, 0);
      acc[0][0] = __builtin_amdgcn_mfma_i32_32x32x32_i8(A0b, B0b, acc[0][0], 0, 0, 0);
      acc[0][1] = __builtin_amdgcn_mfma_i32_32x32x32_i8(A0b, B1b, acc[0][1], 0, 0, 0);
      acc[1][0] = __builtin_amdgcn_mfma_i32_32x32x32_i8(A1b, B0b, acc[1][0], 0, 0, 0);
      acc[1][1] = __builtin_amdgcn_mfma_i32_32x32x32_i8(A1b, B1b, acc[1][1], 0, 0, 0);
    }
    // acc[si][sj][r]: seq = 32si + 8(r>>2) + 4hi + (r&3), ch(d) = 32sj + l31
    const float a_in = scal[0], vact = scal[3];
#pragma unroll
    for (int sj = 0; sj < 2; sj++) {
      int cg = col0 + 32 * sj + l31;
      float bq = biasq[cg];
      float va = fdiv(vact, fmul(a_in, qkv_alpha[cg]));
      int dloc = 32 * sj + l31;
#pragma unroll
      for (int si = 0; si < 2; si++)
#pragma unroll
        for (int b = 0; b < 4; b++) {
          uint32_t pk = 0;
#pragma unroll
          for (int c = 0; c < 4; c++) {
            float vint = fadd((float)acc[si][sj][4 * b + c], bq);
            float t = fminf(fmaxf(fdiv(vint, va), -4.f), 3.f);
            pk |= ((uint32_t)(uint8_t)(int8_t)rintf(t)) << (8 * c);
          }
          *(uint32_t*)&packT[w][dloc * 80 + 32 * si + 8 * b + 4 * hi] = pk;
        }
    }
    asm volatile("s_waitcnt lgkmcnt(0)" ::: "memory");
#pragma unroll
    for (int c = 0; c < 4; c++) {
      int row = 16 * c + (lane >> 2), off = (lane & 3) * 16;  // row = d
      int4 ov = *(const int4*)&packT[w][row * 80 + off];
      *(int4*)(v2t + (bh * HD + row) * NN + nbase + w64 + off) = ov;
    }
  }
}

// ---------------------------------------------------------------------------
// Attention (i8 MFMA), per (qtile64, b*h) — unchanged from R4 (verified).
// ---------------------------------------------------------------------------
__global__ __launch_bounds__(256) void attn_kernel(
    const int8_t* __restrict__ q2, const int8_t* __restrict__ k2,
    const int8_t* __restrict__ v2t, const float* __restrict__ scal,
    int8_t* __restrict__ x1q) {
  __shared__ __align__(16) int8_t Qs[64][80];
  __shared__ __align__(16) int8_t Ks[64][80];
  __shared__ __align__(16) int8_t Vt[64][80];
  __shared__ __align__(16) int8_t At[64][80];

  const int qt = blockIdx.x, bh = blockIdx.y;
  const int tid = threadIdx.x;
  const int w = tid >> 6, lane = tid & 63, quad = lane >> 4, c16 = lane & 15;
  const int sr = tid >> 2, scol = (tid & 3) << 4;
  const float attnm = scal[4];
  const float coef =
      fmul(1.4426950408889634f, fmul(fmul(0.125f, scal[1]), scal[2]));
  const float coef128 = fmul(coef, 128.f);
  const size_t base = (size_t)bh * NN * HD;

  *(int4*)&Qs[sr][scol] =
      *(const int4*)(q2 + base + (size_t)(qt * 64 + sr) * HD + scol);
  __syncthreads();
  v4i qf = *(const v4i*)&Qs[16 * w + c16][quad * 16];

  // ---- pass A: QK^T, m -> registers, row sums of 2^m ----
  uint32_t mpack[8][4];
  float Srow = 0.f;
  int4 kv = *(const int4*)(k2 + base + (size_t)sr * HD + scol);
#pragma unroll
  for (int kt = 0; kt < 8; kt++) {
    *(int4*)&Ks[sr][scol] = kv;
    __syncthreads();
    if (kt < 7)
      kv = *(const int4*)(k2 + base + (size_t)((kt + 1) * 64 + sr) * HD + scol);
    float psum = 0.f;
#pragma unroll
    for (int f = 0; f < 4; f++) {
      v4i kf = *(const v4i*)&Ks[16 * f + c16][quad * 16];
      v4i d2 = (v4i){0, 0, 0, 0};
      d2 = __builtin_amdgcn_mfma_i32_16x16x64_i8(kf, qf, d2, 0, 0, 0);
      uint32_t pk = 0;
#pragma unroll
      for (int r = 0; r < 4; r++) {
        float e = truncf(fmul(coef128, (float)d2[r]));
        int mi = (int)rintf(fmul(e, 0.0078125f));
        psum = fadd(psum, ldexpf(1.0f, mi));
        pk |= ((uint32_t)(uint8_t)(int8_t)mi) << (8 * r);
      }
      mpack[kt][f] = pk;
    }
    psum = fadd(psum, __shfl_xor(psum, 16, 64));
    psum = fadd(psum, __shfl_xor(psum, 32, 64));
    Srow = fadd(Srow, psum);
    __syncthreads();
  }
  const float u = fdiv(fdiv(1.0f, Srow), attnm);

  // ---- pass B: requantize from register m, AV ----
  v4i xacc[4];
#pragma unroll
  for (int s = 0; s < 4; s++) xacc[s] = (v4i){0, 0, 0, 0};

  int4 vv = *(const int4*)(v2t + ((size_t)bh * HD + sr) * NN + scol);
#pragma unroll
  for (int kt = 0; kt < 8; kt++) {
    *(int4*)&Vt[sr][scol] = vv;
    __syncthreads();
    if (kt < 7)
      vv = *(const int4*)(v2t + ((size_t)bh * HD + sr) * NN + (kt + 1) * 64 +
                          scol);
#pragma unroll
    for (int f = 0; f < 4; f++) {
      uint32_t pk = mpack[kt][f];
      uint32_t wpk = 0;
#pragma unroll
      for (int r = 0; r < 4; r++) {
        int mi = (int)(int8_t)(pk >> (8 * r));
        float t = fminf(ldexpf(u, mi), 7.f);
        wpk |= ((uint32_t)(uint8_t)(int8_t)rintf(t)) << (8 * r);
      }
      *(uint32_t*)&At[16 * w + c16][16 * f + 4 * quad] = wpk;
    }
    asm volatile("s_waitcnt lgkmcnt(0)" ::: "memory");
    v4i af = *(const v4i*)&At[16 * w + c16][quad * 16];
#pragma unroll
    for (int s = 0; s < 4; s++) {
      v4i vf = *(const v4i*)&Vt[16 * s + c16][quad * 16];
      xacc[s] = __builtin_amdgcn_mfma_i32_16x16x64_i8(vf, af, xacc[s], 0, 0, 0);
    }
    __syncthreads();
  }

  const float pa = fdiv(scal[5], fmul(attnm, scal[3]));
#pragma unroll
  for (int s = 0; s < 4; s++) {
    uint32_t pack = 0;
#pragma unroll
    for (int r = 0; r < 4; r++) {
      float t = fminf(fmaxf(fdiv((float)xacc[s][r], pa), -4.f), 3.f);
      pack |= ((uint32_t)(uint8_t)(int8_t)rintf(t)) << (8 * r);
    }
    *(uint32_t*)&Ks[16 * w + c16][16 * s + 4 * quad] = pack;
  }
  __syncthreads();
  int4 ov = *(const int4*)&Ks[sr][scol];
  *(int4*)(x1q + ((size_t)bh * NN + qt * 64 + sr) * HD + scol) = ov;
}

// ---------------------------------------------------------------------------
// GEMM2 (i8 MFMA 32x32x32): barrier-free, LDS-free.  Block = 256seq x 64ch,
// wave = 64x64.  A = x1q [bh][n][64] (head slice = kt, coalesced rows);
// B = pwq tiled [12][768][64].  D = W*X^T; float4 epilogue stores.
// ---------------------------------------------------------------------------
__global__ __launch_bounds__(256, 4) void gemm_proj_kernel(
    const int8_t* __restrict__ x1q, const int8_t* __restrict__ Wq,
    const float* __restrict__ proj_alpha, const float* __restrict__ proj_bias,
    const float* __restrict__ scal, float* __restrict__ out) {
  const int g = blockIdx.x, rb = blockIdx.y;
  const int tid = threadIdx.x;
  const int w = tid >> 6, lane = tid & 63;
  const int l31 = lane & 31, hi = lane >> 5;
  const int col0 = g * 64;
  const int b_idx = rb >> 1, nbase = (rb & 1) * 256;
  const int w64 = w * 64;

  v16i acc[2][2];
#pragma unroll
  for (int i = 0; i < 2; i++)
#pragma unroll
    for (int j = 0; j < 2; j++) acc[i][j] = (v16i)(0);

  const int8_t* pa0 =
      x1q + ((size_t)b_idx * HH * NN + nbase + w64 + l31) * 64 + hi * 16;
  const int8_t* pa1 = pa0 + 32 * 64;
  const int8_t* pb0 = Wq + ((size_t)(col0 + l31)) * 64 + hi * 16;
  const int8_t* pb1 = pb0 + 32 * 64;
  const size_t KTX = (size_t)NN * 64;  // head stride in x1q

#pragma unroll
  for (int kt = 0; kt < 12; kt++) {
    v4i A0a = *(const v4i*)(pa0 + kt * KTX);
    v4i A1a = *(const v4i*)(pa1 + kt * KTX);
    v4i B0a = *(const v4i*)(pb0 + kt * KTP);
    v4i B1a = *(const v4i*)(pb1 + kt * KTP);
    v4i A0b = *(const v4i*)(pa0 + kt * KTX + 32);
    v4i A1b = *(const v4i*)(pa1 + kt * KTX + 32);
    v4i B0b = *(const v4i*)(pb0 + kt * KTP + 32);
    v4i B1b = *(const v4i*)(pb1 + kt * KTP + 32);
    acc[0][0] = __builtin_amdgcn_mfma_i32_32x32x32_i8(B0a, A0a, acc[0][0], 0, 0, 0);
    acc[0][1] = __builtin_amdgcn_mfma_i32_32x32x32_i8(B0a, A1a, acc[0][1], 0, 0, 0);
    acc[1][0] = __builtin_amdgcn_mfma_i32_32x32x32_i8(B1a, A0a, acc[1][0], 0, 0, 0);
    acc[1][1] = __builtin_amdgcn_mfma_i32_32x32x32_i8(B1a, A1a, acc[1][1], 0, 0, 0);
    acc[0][0] = __builtin_amdgcn_mfma_i32_32x32x32_i8(B0b, A0b, acc[0][0], 0, 0, 0);
    acc[0][1] = __builtin_amdgcn_mfma_i32_32x32x32_i8(B0b, A1b, acc[0][1], 0, 0, 0);
    acc[1][0] = __builtin_amdgcn_mfma_i32_32x32x32_i8(B1b, A0b, acc[1][0], 0, 0, 0);
    acc[1][1] = __builtin_amdgcn_mfma_i32_32x32x32_i8(B1b, A1b, acc[1][1], 0, 0, 0);
  }

  const float pact = scal[5];
  const int seqbase = rb * 256 + w64;
#pragma unroll
  for (int i = 0; i < 2; i++)
#pragma unroll
    for (int b = 0; b < 4; b++) {
      int colb = col0 + 32 * i + 8 * b + 4 * hi;
      float4 al = *(const float4*)(proj_alpha + colb);
      float4 bi = *(const float4*)(proj_bias + colb);
      const float* alp = (const float*)&al;
      const float* bip = (const float*)&bi;
#pragma unroll
      for (int j = 0; j < 2; j++) {
        int m = seqbase + 32 * j + l31;
        float4 o;
        float* op = (float*)&o;
#pragma unroll
        for (int c = 0; c < 4; c++)
          op[c] = fadd(fmul(fmul((float)acc[i][j][4 * b + c], alp[c]), pact),
                       bip[c]);
        *(float4*)(out + (size_t)m * CC + colb) = o;
      }
    }
}

extern "C" void kernel_launch(void* const* d_in, const int* in_sizes, int n_in,
                              void* d_out, int out_size, void* d_ws,
                              size_t ws_size, hipStream_t stream) {
  const float* x0 = (const float*)d_in[0];
  const float* qkv_w = (const float*)d_in[1];
  const float* qkv_alpha = (const float*)d_in[2];
  const float* qkv_bias = (const float*)d_in[3];
  const float* qkv_act_alpha = (const float*)d_in[4];
  const float* proj_w = (const float*)d_in[5];
  const float* proj_alpha = (const float*)d_in[6];
  const float* proj_bias = (const float*)d_in[7];
  const float* proj_act_alpha = (const float*)d_in[8];
  const float* normq_w = (const float*)d_in[9];
  const float* normq_b = (const float*)d_in[10];
  const float* normk_w = (const float*)d_in[11];
  const float* normk_b = (const float*)d_in[12];
  const float* qact_alpha = (const float*)d_in[13];
  const float* kact_alpha = (const float*)d_in[14];
  const float* vact_alpha = (const float*)d_in[15];
  const float* attnact_alpha = (const float*)d_in[16];

  char* ws = (char*)d_ws;
  size_t off = 0;
  auto alloc = [&](size_t bytes) -> char* {
    char* p = ws + off;
    off += (bytes + 255) & ~(size_t)255;
    return p;
  };
  float* scal = (float*)alloc(64 * 4);
  float* qparams = (float*)alloc(256 * 4);
  float* biasq = (float*)alloc(QKV_C * 4);
  int8_t* x0q = (int8_t*)alloc((size_t)M_ROWS * CC);   // tiled [12][16384][64]
  int8_t* wq = (int8_t*)alloc((size_t)QKV_C * CC);     // tiled [12][2304][64]
  int8_t* pwq = (int8_t*)alloc((size_t)CC * CC);       // tiled [12][768][64]
  int8_t* q2 = (int8_t*)alloc((size_t)BB * HH * NN * HD);
  int8_t* k2 = (int8_t*)alloc((size_t)BB * HH * NN * HD);
  int8_t* v2t = (int8_t*)alloc((size_t)BB * HH * NN * HD);
  int8_t* x1q = (int8_t*)alloc((size_t)M_ROWS * CC);

  prep_kernel<<<1, 256, 0, stream>>>(qkv_act_alpha, proj_act_alpha, qact_alpha,
                                     kact_alpha, vact_alpha, attnact_alpha,
                                     normq_w, normq_b, normk_w, normk_b,
                                     qkv_bias, qkv_alpha, scal, qparams, biasq);

  int total4 = M_ROWS * CC / 4;
  quant_x0_kernel<<<(total4 + 255) / 256, 256, 0, stream>>>(x0, scal, x0q,
                                                            total4);
  quant_w_kernel<<<(QKV_C * CC + 255) / 256, 256, 0, stream>>>(
      qkv_w, qkv_alpha, wq, QKV_C, QKV_C * CC);
  quant_w_kernel<<<(CC * CC + 255) / 256, 256, 0, stream>>>(
      proj_w, proj_alpha, pwq, CC, CC * CC);

  gemm_qkv_kernel<<<dim3(QKV_C / 64, M_ROWS / 256), 256, 0, stream>>>(
      x0q, wq, biasq, scal, qkv_alpha, qparams, q2, k2, v2t);

  attn_kernel<<<dim3(NN / 64, BB * HH), 256, 0, stream>>>(q2, k2, v2t, scal,
                                                          x1q);

  gemm_proj_kernel<<<dim3(CC / 64, M_ROWS / 256), 256, 0, stream>>>(
      x1q, pwq, proj_alpha, proj_bias, scal, (float*)d_out);
}

// Round 6
// 361.134 us; speedup vs baseline: 6.7637x; 1.0024x over previous
//
#include <hip/hip_runtime.h>
#include <stdint.h>

// ---------------------------------------------------------------------------
// Q_Attention: quantized ViT attention block, bit-faithful to the JAX/numpy ref.
// B=32, N=512, C=768, H=12, hd=64.  All GEMMs on i8 MFMA (int32 acc, exact).
// R6: XCD-affine block swizzle.  All grids linearized; blocks sharing an
// A-slice (gemm) or a K/V head (attn) decode to the SAME XCD (id%8) in
// consecutive dispatch slots, so the shared bytes stay in that XCD's L2
// (per-XCD L2s are not cross-coherent; reuse across XCDs = HBM refetch).
// Arithmetic identical to R5 (absmax 0.0 verified structure).
// ---------------------------------------------------------------------------

#define BB 32
#define NN 512
#define CC 768
#define HH 12
#define HD 64
#define M_ROWS (BB * NN)     // 16384
#define QKV_C (3 * CC)       // 2304
#define KTA ((size_t)M_ROWS * 64)   // x0q kt-slice stride
#define KTB ((size_t)QKV_C * 64)    // wq  kt-slice stride
#define KTP ((size_t)CC * 64)       // pwq kt-slice stride

typedef int v4i __attribute__((ext_vector_type(4)));
typedef int v16i __attribute__((ext_vector_type(16)));

__device__ __forceinline__ float fadd(float a, float b) { return __fadd_rn(a, b); }
__device__ __forceinline__ float fmul(float a, float b) { return __fmul_rn(a, b); }
__device__ __forceinline__ float fdiv(float a, float b) { return __fdiv_rn(a, b); }
__device__ __forceinline__ float fsub(float a, float b) { return __fsub_rn(a, b); }

// numpy pairwise_sum, n=96 (no remainder): 8 accumulators, then pairwise combine
__device__ float np_sum_96(const float* a) {
  float r[8];
#pragma unroll
  for (int j = 0; j < 8; j++) r[j] = a[j];
  for (int i = 8; i < 96; i += 8)
#pragma unroll
    for (int j = 0; j < 8; j++) r[j] = fadd(r[j], a[i + j]);
  return fadd(fadd(fadd(r[0], r[1]), fadd(r[2], r[3])),
              fadd(fadd(r[4], r[5]), fadd(r[6], r[7])));
}

// numpy pairwise mean of 12: 8-acc combine + 4 sequential remainder adds
__device__ float np_mean_12(const float* a) {
  float r[8];
#pragma unroll
  for (int j = 0; j < 8; j++) r[j] = a[j];
  float res = fadd(fadd(fadd(r[0], r[1]), fadd(r[2], r[3])),
                   fadd(fadd(r[4], r[5]), fadd(r[6], r[7])));
  res = fadd(res, a[8]);
  res = fadd(res, a[9]);
  res = fadd(res, a[10]);
  res = fadd(res, a[11]);
  return fdiv(res, 12.0f);
}

// ---------------------------------------------------------------------------
// prep: scalar means + folded LN quant params + integer qkv bias
// scal: [0]=a_in [1]=qact_m [2]=kact_m [3]=vact_m [4]=attnact_m [5]=pact_m
// qparams: [0:64]=qalpha [64:128]=qbias [128:192]=kalpha [192:256]=kbias
// ---------------------------------------------------------------------------
__global__ void prep_kernel(const float* __restrict__ qkv_act_alpha,
                            const float* __restrict__ proj_act_alpha,
                            const float* __restrict__ qact_alpha,
                            const float* __restrict__ kact_alpha,
                            const float* __restrict__ vact_alpha,
                            const float* __restrict__ attnact_alpha,
                            const float* __restrict__ normq_w,
                            const float* __restrict__ normq_b,
                            const float* __restrict__ normk_w,
                            const float* __restrict__ normk_b,
                            const float* __restrict__ qkv_bias,
                            const float* __restrict__ qkv_alpha,
                            float* __restrict__ scal,
                            float* __restrict__ qparams,
                            float* __restrict__ biasq) {
  __shared__ float s_scal[8];
  __shared__ float chunk[16];
  int tid = threadIdx.x;
  if (tid < 8) chunk[tid] = np_sum_96(qkv_act_alpha + 96 * tid);
  else if (tid < 16) chunk[tid] = np_sum_96(proj_act_alpha + 96 * (tid - 8));
  if (tid == 16) s_scal[1] = np_mean_12(qact_alpha);
  if (tid == 17) s_scal[2] = np_mean_12(kact_alpha);
  if (tid == 18) s_scal[3] = np_mean_12(vact_alpha);
  if (tid == 19) s_scal[4] = np_mean_12(attnact_alpha);
  __syncthreads();
  if (tid == 0) {
    float s0 = fadd(fadd(chunk[0], chunk[1]), fadd(chunk[2], chunk[3]));
    float s1 = fadd(fadd(chunk[4], chunk[5]), fadd(chunk[6], chunk[7]));
    s_scal[0] = fdiv(fadd(s0, s1), 768.0f);
    float p0 = fadd(fadd(chunk[8], chunk[9]), fadd(chunk[10], chunk[11]));
    float p1 = fadd(fadd(chunk[12], chunk[13]), fadd(chunk[14], chunk[15]));
    s_scal[5] = fdiv(fadd(p0, p1), 768.0f);
  }
  __syncthreads();
  if (tid < 6) scal[tid] = s_scal[tid];
  if (tid < 64) {
    qparams[tid]       = fdiv(s_scal[1], normq_w[tid]);    // act_a / nw
    qparams[64 + tid]  = fdiv(normq_b[tid], normq_w[tid]); // nb / nw
    qparams[128 + tid] = fdiv(s_scal[2], normk_w[tid]);
    qparams[192 + tid] = fdiv(normk_b[tid], normk_w[tid]);
  }
  float a_in = s_scal[0];
  for (int c = tid; c < QKV_C; c += blockDim.x)
    biasq[c] = truncf(fdiv(fdiv(qkv_bias[c], a_in), qkv_alpha[c]));
}

// x0_q = round(clip(x0 / a_in, -8, 7)) -> int8, K-TILED layout [12][16384][64]
__global__ void quant_x0_kernel(const float* __restrict__ x0,
                                const float* __restrict__ scal,
                                int8_t* __restrict__ x0q, int total4) {
  int i = blockIdx.x * blockDim.x + threadIdx.x;
  if (i >= total4) return;
  float a_in = scal[0];
  float4 v = ((const float4*)x0)[i];
  char4 o;
  o.x = (int8_t)rintf(fminf(fmaxf(fdiv(v.x, a_in), -8.f), 7.f));
  o.y = (int8_t)rintf(fminf(fmaxf(fdiv(v.y, a_in), -8.f), 7.f));
  o.z = (int8_t)rintf(fminf(fmaxf(fdiv(v.z, a_in), -8.f), 7.f));
  o.w = (int8_t)rintf(fminf(fmaxf(fdiv(v.w, a_in), -8.f), 7.f));
  int seq = i / 192;
  int kp = (i - seq * 192) * 4;
  *(char4*)(x0q + ((size_t)(kp >> 6) * M_ROWS + seq) * 64 + (kp & 63)) = o;
}

// row-wise 4-bit weight quant -> K-TILED layout [CC/64][rows][64]
__global__ void quant_w_kernel(const float* __restrict__ w,
                               const float* __restrict__ alpha,
                               int8_t* __restrict__ wq, int rows, int total) {
  int i = blockIdx.x * blockDim.x + threadIdx.x;
  if (i >= total) return;
  int row = i / CC;
  int k = i - row * CC;
  float t = fminf(fmaxf(fdiv(w[i], alpha[row]), -8.f), 7.f);
  wq[((size_t)(k >> 6) * rows + row) * 64 + (k & 63)] =
      (int8_t)rintf(t);
}

// ---------------------------------------------------------------------------
// GEMM1 (i8 MFMA 32x32x32): barrier-free.  Block = 256seq x 64ch; 4 waves
// each own 64x64.  XCD-affine decode: xcd = L&7; s = L>>3; rb = xcd + 8*(s/36)
// (A row-slice), g = s%36 (column head).  All 36 sharers of one 196KB A-slice
// run consecutively on ONE XCD -> A slice L2-resident, fetched once.
// q/k: D = W*X^T, register LN (numpy 8-acc order); v: D = X*W^T transpose.
// ---------------------------------------------------------------------------
__global__ __launch_bounds__(256, 4) void gemm_qkv_kernel(
    const int8_t* __restrict__ Aq, const int8_t* __restrict__ Wq,
    const float* __restrict__ biasq, const float* __restrict__ scal,
    const float* __restrict__ qkv_alpha, const float* __restrict__ qparams,
    int8_t* __restrict__ q2, int8_t* __restrict__ k2,
    int8_t* __restrict__ v2t) {
  __shared__ __align__(16) int8_t packT[4][5120];  // [wave][64 rows x 80]

  const int L = blockIdx.x;
  const int xcd = L & 7, s = L >> 3;
  const int rb = xcd + 8 * (s / 36);   // A row-slice 0..63 (XCD-resident)
  const int g = s % 36;                // column head 0..35
  const int tid = threadIdx.x;
  const int w = tid >> 6, lane = tid & 63;
  const int l31 = lane & 31, hi = lane >> 5;
  const int sec = g / HH, head = g % HH;
  const int col0 = g * 64;
  const int b_idx = rb >> 1, nbase = (rb & 1) * 256;
  const int w64 = w * 64;
  const size_t bh = (size_t)b_idx * HH + head;

  v16i acc[2][2];
#pragma unroll
  for (int i = 0; i < 2; i++)
#pragma unroll
    for (int j = 0; j < 2; j++) acc[i][j] = (v16i)(0);

  const int8_t* pa0 = Aq + ((size_t)(rb * 256 + w64 + l31)) * 64 + hi * 16;
  const int8_t* pa1 = pa0 + 32 * 64;
  const int8_t* pb0 = Wq + ((size_t)(col0 + l31)) * 64 + hi * 16;
  const int8_t* pb1 = pb0 + 32 * 64;

  if (sec < 2) {  // q/k: D = W * X^T
#pragma unroll
    for (int kt = 0; kt < 12; kt++) {
      v4i A0a = *(const v4i*)(pa0 + kt * KTA);
      v4i A1a = *(const v4i*)(pa1 + kt * KTA);
      v4i B0a = *(const v4i*)(pb0 + kt * KTB);
      v4i B1a = *(const v4i*)(pb1 + kt * KTB);
      v4i A0b = *(const v4i*)(pa0 + kt * KTA + 32);
      v4i A1b = *(const v4i*)(pa1 + kt * KTA + 32);
      v4i B0b = *(const v4i*)(pb0 + kt * KTB + 32);
      v4i B1b = *(const v4i*)(pb1 + kt * KTB + 32);
      acc[0][0] = __builtin_amdgcn_mfma_i32_32x32x32_i8(B0a, A0a, acc[0][0], 0, 0, 0);
      acc[0][1] = __builtin_amdgcn_mfma_i32_32x32x32_i8(B0a, A1a, acc[0][1], 0, 0, 0);
      acc[1][0] = __builtin_amdgcn_mfma_i32_32x32x32_i8(B1a, A0a, acc[1][0], 0, 0, 0);
      acc[1][1] = __builtin_amdgcn_mfma_i32_32x32x32_i8(B1a, A1a, acc[1][1], 0, 0, 0);
      acc[0][0] = __builtin_amdgcn_mfma_i32_32x32x32_i8(B0b, A0b, acc[0][0], 0, 0, 0);
      acc[0][1] = __builtin_amdgcn_mfma_i32_32x32x32_i8(B0b, A1b, acc[0][1], 0, 0, 0);
      acc[1][0] = __builtin_amdgcn_mfma_i32_32x32x32_i8(B1b, A0b, acc[1][0], 0, 0, 0);
      acc[1][1] = __builtin_amdgcn_mfma_i32_32x32x32_i8(B1b, A1b, acc[1][1], 0, 0, 0);
    }
    // ---- epilogue: x = (acc + biasq)*alpha; register LN; 3b quant ----
    // acc[i][j][r]: ch = col0 + 32i + 8(r>>2) + 4hi + (r&3), seq = 32j + l31
    float xs[2][2][16];
#pragma unroll
    for (int i = 0; i < 2; i++)
#pragma unroll
      for (int b = 0; b < 4; b++) {
        int cg = col0 + 32 * i + 8 * b + 4 * hi;
        float4 bqv = *(const float4*)(biasq + cg);
        float4 alv = *(const float4*)(qkv_alpha + cg);
        const float* bqp = (const float*)&bqv;
        const float* alp = (const float*)&alv;
#pragma unroll
        for (int j = 0; j < 2; j++)
#pragma unroll
          for (int c = 0; c < 4; c++)
            xs[i][j][4 * b + c] =
                fmul(fadd((float)acc[i][j][4 * b + c], bqp[c]), alp[c]);
      }
    // numpy-order stats: acc index = ch&7 = 4hi+c (lane-local!), t = ch>>3 = 4i+b
    float mean[2], den[2];
#pragma unroll
    for (int j = 0; j < 2; j++) {
      float rc[4];
#pragma unroll
      for (int c = 0; c < 4; c++) rc[c] = xs[0][j][c];
#pragma unroll
      for (int b = 1; b < 4; b++)
#pragma unroll
        for (int c = 0; c < 4; c++) rc[c] = fadd(rc[c], xs[0][j][4 * b + c]);
#pragma unroll
      for (int b = 0; b < 4; b++)
#pragma unroll
        for (int c = 0; c < 4; c++) rc[c] = fadd(rc[c], xs[1][j][4 * b + c]);
      float L2 = fadd(fadd(rc[0], rc[1]), fadd(rc[2], rc[3]));
      float R = __shfl_xor(L2, 32, 64);
      float mn = fdiv(fadd(L2, R), 64.0f);  // fadd commutative -> both lanes equal
      float vc[4];
#pragma unroll
      for (int c = 0; c < 4; c++) {
        float d = fsub(xs[0][j][c], mn);
        vc[c] = fmul(d, d);
      }
#pragma unroll
      for (int b = 1; b < 4; b++)
#pragma unroll
        for (int c = 0; c < 4; c++) {
          float d = fsub(xs[0][j][4 * b + c], mn);
          vc[c] = fadd(vc[c], fmul(d, d));
        }
#pragma unroll
      for (int b = 0; b < 4; b++)
#pragma unroll
        for (int c = 0; c < 4; c++) {
          float d = fsub(xs[1][j][4 * b + c], mn);
          vc[c] = fadd(vc[c], fmul(d, d));
        }
      float Lv = fadd(fadd(vc[0], vc[1]), fadd(vc[2], vc[3]));
      float Rv = __shfl_xor(Lv, 32, 64);
      float var = fdiv(fadd(Lv, Rv), 63.0f);
      mean[j] = mn;
      den[j] = fadd(__fsqrt_rn(var), 1e-5f);
    }
    const float* ap = qparams + (sec == 0 ? 0 : 128);
#pragma unroll
    for (int i = 0; i < 2; i++)
#pragma unroll
      for (int b = 0; b < 4; b++) {
        int cin = 32 * i + 8 * b + 4 * hi;  // channel-in-head
        float4 a4 = *(const float4*)(ap + cin);
        float4 b4 = *(const float4*)(ap + 64 + cin);
        const float* a4p = (const float*)&a4;
        const float* b4p = (const float*)&b4;
#pragma unroll
        for (int j = 0; j < 2; j++) {
          uint32_t pk = 0;
#pragma unroll
          for (int c = 0; c < 4; c++) {
            float xn = fdiv(fsub(xs[i][j][4 * b + c], mean[j]), den[j]);
            float t = fdiv(fadd(xn, b4p[c]), a4p[c]);
            t = fminf(fmaxf(t, -4.f), 3.f);
            pk |= ((uint32_t)(uint8_t)(int8_t)rintf(t)) << (8 * c);
          }
          *(uint32_t*)&packT[w][(32 * j + l31) * 80 + cin] = pk;
        }
      }
    asm volatile("s_waitcnt lgkmcnt(0)" ::: "memory");
    int8_t* dst = (sec == 0) ? q2 : k2;
    size_t rowbase = bh * NN + nbase + w64;
#pragma unroll
    for (int c = 0; c < 4; c++) {
      int row = 16 * c + (lane >> 2), off = (lane & 3) * 16;
      int4 ov = *(const int4*)&packT[w][row * 80 + off];
      *(int4*)(dst + (rowbase + row) * 64 + off) = ov;
    }
  } else {  // v: D = X * W^T (row = seq -> dword-packed transpose)
#pragma unroll
    for (int kt = 0; kt < 12; kt++) {
      v4i A0a = *(const v4i*)(pa0 + kt * KTA);
      v4i A1a = *(const v4i*)(pa1 + kt * KTA);
      v4i B0a = *(const v4i*)(pb0 + kt * KTB);
      v4i B1a = *(const v4i*)(pb1 + kt * KTB);
      v4i A0b = *(const v4i*)(pa0 + kt * KTA + 32);
      v4i A1b = *(const v4i*)(pa1 + kt * KTA + 32);
      v4i B0b = *(const v4i*)(pb0 + kt * KTB + 32);
      v4i B1b = *(const v4i*)(pb1 + kt * KTB + 32);
      // acc[si][sj]: si = seq block, sj = ch block
      acc[0][0] = __builtin_amdgcn_mfma_i32_32x32x32_i8(A0a, B0a, acc[0][0], 0, 0, 0);
      acc[0][1] = __builtin_amdgcn_mfma_i32_32x32x32_i8(A0a, B1a, acc[0][1], 0, 0, 0);
      acc[1][0] = __builtin_amdgcn_mfma_i32_32x32x32_i8(A1a, B0a, acc[1][0], 0, 0, 0);
      acc[1][1] = __builtin_amdgcn_mfma_i32_32x32x32_i8(A1a, B1a, acc[1][1], 0, 0, 0);
      acc[0][0] = __builtin_amdgcn_mfma_i32_32x32x32_i8(A0b, B0b, acc[0][0], 0, 0, 0);
      acc[0][1] = __builtin_amdgcn_mfma_i32_32x32x32_i8(A0b, B1b, acc[0][1], 0, 0, 0);
      acc[1][0] = __builtin_amdgcn_mfma_i32_32x32x32_i8(A1b, B0b, acc[1][0], 0, 0, 0);
      acc[1][1] = __builtin_amdgcn_mfma_i32_32x32x32_i8(A1b, B1b, acc[1][1], 0, 0, 0);
    }
    // acc[si][sj][r]: seq = 32si + 8(r>>2) + 4hi + (r&3), ch(d) = 32sj + l31
    const float a_in = scal[0], vact = scal[3];
#pragma unroll
    for (int sj = 0; sj < 2; sj++) {
      int cg = col0 + 32 * sj + l31;
      float bq = biasq[cg];
      float va = fdiv(vact, fmul(a_in, qkv_alpha[cg]));
      int dloc = 32 * sj + l31;
#pragma unroll
      for (int si = 0; si < 2; si++)
#pragma unroll
        for (int b = 0; b < 4; b++) {
          uint32_t pk = 0;
#pragma unroll
          for (int c = 0; c < 4; c++) {
            float vint = fadd((float)acc[si][sj][4 * b + c], bq);
            float t = fminf(fmaxf(fdiv(vint, va), -4.f), 3.f);
            pk |= ((uint32_t)(uint8_t)(int8_t)rintf(t)) << (8 * c);
          }
          *(uint32_t*)&packT[w][dloc * 80 + 32 * si + 8 * b + 4 * hi] = pk;
        }
    }
    asm volatile("s_waitcnt lgkmcnt(0)" ::: "memory");
#pragma unroll
    for (int c = 0; c < 4; c++) {
      int row = 16 * c + (lane >> 2), off = (lane & 3) * 16;  // row = d
      int4 ov = *(const int4*)&packT[w][row * 80 + off];
      *(int4*)(v2t + (bh * HD + row) * NN + nbase + w64 + off) = ov;
    }
  }
}

// ---------------------------------------------------------------------------
// Attention (i8 MFMA), per (qtile64, b*h).  XCD-affine decode: the 8 qt-blocks
// of one (b,h) head run consecutively on one XCD -> K/V head L2-resident.
// ---------------------------------------------------------------------------
__global__ __launch_bounds__(256) void attn_kernel(
    const int8_t* __restrict__ q2, const int8_t* __restrict__ k2,
    const int8_t* __restrict__ v2t, const float* __restrict__ scal,
    int8_t* __restrict__ x1q) {
  __shared__ __align__(16) int8_t Qs[64][80];
  __shared__ __align__(16) int8_t Ks[64][80];
  __shared__ __align__(16) int8_t Vt[64][80];
  __shared__ __align__(16) int8_t At[64][80];

  const int L = blockIdx.x;
  const int xcd = L & 7, s = L >> 3;
  const int bh = xcd + 8 * (s >> 3);   // head 0..383 (XCD-resident K/V)
  const int qt = s & 7;                // q tile 0..7
  const int tid = threadIdx.x;
  const int w = tid >> 6, lane = tid & 63, quad = lane >> 4, c16 = lane & 15;
  const int sr = tid >> 2, scol = (tid & 3) << 4;
  const float attnm = scal[4];
  const float coef =
      fmul(1.4426950408889634f, fmul(fmul(0.125f, scal[1]), scal[2]));
  const float coef128 = fmul(coef, 128.f);
  const size_t base = (size_t)bh * NN * HD;

  *(int4*)&Qs[sr][scol] =
      *(const int4*)(q2 + base + (size_t)(qt * 64 + sr) * HD + scol);
  __syncthreads();
  v4i qf = *(const v4i*)&Qs[16 * w + c16][quad * 16];

  // ---- pass A: QK^T, m -> registers, row sums of 2^m ----
  uint32_t mpack[8][4];
  float Srow = 0.f;
  int4 kv = *(const int4*)(k2 + base + (size_t)sr * HD + scol);
#pragma unroll
  for (int kt = 0; kt < 8; kt++) {
    *(int4*)&Ks[sr][scol] = kv;
    __syncthreads();
    if (kt < 7)
      kv = *(const int4*)(k2 + base + (size_t)((kt + 1) * 64 + sr) * HD + scol);
    float psum = 0.f;
#pragma unroll
    for (int f = 0; f < 4; f++) {
      v4i kf = *(const v4i*)&Ks[16 * f + c16][quad * 16];
      v4i d2 = (v4i){0, 0, 0, 0};
      d2 = __builtin_amdgcn_mfma_i32_16x16x64_i8(kf, qf, d2, 0, 0, 0);
      uint32_t pk = 0;
#pragma unroll
      for (int r = 0; r < 4; r++) {
        float e = truncf(fmul(coef128, (float)d2[r]));
        int mi = (int)rintf(fmul(e, 0.0078125f));
        psum = fadd(psum, ldexpf(1.0f, mi));
        pk |= ((uint32_t)(uint8_t)(int8_t)mi) << (8 * r);
      }
      mpack[kt][f] = pk;
    }
    psum = fadd(psum, __shfl_xor(psum, 16, 64));
    psum = fadd(psum, __shfl_xor(psum, 32, 64));
    Srow = fadd(Srow, psum);
    __syncthreads();
  }
  const float u = fdiv(fdiv(1.0f, Srow), attnm);

  // ---- pass B: requantize from register m, AV ----
  v4i xacc[4];
#pragma unroll
  for (int s2 = 0; s2 < 4; s2++) xacc[s2] = (v4i){0, 0, 0, 0};

  int4 vv = *(const int4*)(v2t + ((size_t)bh * HD + sr) * NN + scol);
#pragma unroll
  for (int kt = 0; kt < 8; kt++) {
    *(int4*)&Vt[sr][scol] = vv;
    __syncthreads();
    if (kt < 7)
      vv = *(const int4*)(v2t + ((size_t)bh * HD + sr) * NN + (kt + 1) * 64 +
                          scol);
#pragma unroll
    for (int f = 0; f < 4; f++) {
      uint32_t pk = mpack[kt][f];
      uint32_t wpk = 0;
#pragma unroll
      for (int r = 0; r < 4; r++) {
        int mi = (int)(int8_t)(pk >> (8 * r));
        float t = fminf(ldexpf(u, mi), 7.f);
        wpk |= ((uint32_t)(uint8_t)(int8_t)rintf(t)) << (8 * r);
      }
      *(uint32_t*)&At[16 * w + c16][16 * f + 4 * quad] = wpk;
    }
    asm volatile("s_waitcnt lgkmcnt(0)" ::: "memory");
    v4i af = *(const v4i*)&At[16 * w + c16][quad * 16];
#pragma unroll
    for (int s2 = 0; s2 < 4; s2++) {
      v4i vf = *(const v4i*)&Vt[16 * s2 + c16][quad * 16];
      xacc[s2] = __builtin_amdgcn_mfma_i32_16x16x64_i8(vf, af, xacc[s2], 0, 0, 0);
    }
    __syncthreads();
  }

  const float pa = fdiv(scal[5], fmul(attnm, scal[3]));
#pragma unroll
  for (int s2 = 0; s2 < 4; s2++) {
    uint32_t pack = 0;
#pragma unroll
    for (int r = 0; r < 4; r++) {
      float t = fminf(fmaxf(fdiv((float)xacc[s2][r], pa), -4.f), 3.f);
      pack |= ((uint32_t)(uint8_t)(int8_t)rintf(t)) << (8 * r);
    }
    *(uint32_t*)&Ks[16 * w + c16][16 * s2 + 4 * quad] = pack;
  }
  __syncthreads();
  int4 ov = *(const int4*)&Ks[sr][scol];
  *(int4*)(x1q + ((size_t)bh * NN + qt * 64 + sr) * HD + scol) = ov;
}

// ---------------------------------------------------------------------------
// GEMM2 (i8 MFMA 32x32x32): barrier-free, LDS-free.  XCD-affine decode:
// 12 column-blocks sharing one x1q row-slice run on one XCD.
// ---------------------------------------------------------------------------
__global__ __launch_bounds__(256, 4) void gemm_proj_kernel(
    const int8_t* __restrict__ x1q, const int8_t* __restrict__ Wq,
    const float* __restrict__ proj_alpha, const float* __restrict__ proj_bias,
    const float* __restrict__ scal, float* __restrict__ out) {
  const int L = blockIdx.x;
  const int xcd = L & 7, s = L >> 3;
  const int rb = xcd + 8 * (s / 12);   // row-slice 0..63 (XCD-resident)
  const int g = s % 12;                // column block 0..11
  const int tid = threadIdx.x;
  const int w = tid >> 6, lane = tid & 63;
  const int l31 = lane & 31, hi = lane >> 5;
  const int col0 = g * 64;
  const int b_idx = rb >> 1, nbase = (rb & 1) * 256;
  const int w64 = w * 64;

  v16i acc[2][2];
#pragma unroll
  for (int i = 0; i < 2; i++)
#pragma unroll
    for (int j = 0; j < 2; j++) acc[i][j] = (v16i)(0);

  const int8_t* pa0 =
      x1q + ((size_t)b_idx * HH * NN + nbase + w64 + l31) * 64 + hi * 16;
  const int8_t* pa1 = pa0 + 32 * 64;
  const int8_t* pb0 = Wq + ((size_t)(col0 + l31)) * 64 + hi * 16;
  const int8_t* pb1 = pb0 + 32 * 64;
  const size_t KTX = (size_t)NN * 64;  // head stride in x1q

#pragma unroll
  for (int kt = 0; kt < 12; kt++) {
    v4i A0a = *(const v4i*)(pa0 + kt * KTX);
    v4i A1a = *(const v4i*)(pa1 + kt * KTX);
    v4i B0a = *(const v4i*)(pb0 + kt * KTP);
    v4i B1a = *(const v4i*)(pb1 + kt * KTP);
    v4i A0b = *(const v4i*)(pa0 + kt * KTX + 32);
    v4i A1b = *(const v4i*)(pa1 + kt * KTX + 32);
    v4i B0b = *(const v4i*)(pb0 + kt * KTP + 32);
    v4i B1b = *(const v4i*)(pb1 + kt * KTP + 32);
    acc[0][0] = __builtin_amdgcn_mfma_i32_32x32x32_i8(B0a, A0a, acc[0][0], 0, 0, 0);
    acc[0][1] = __builtin_amdgcn_mfma_i32_32x32x32_i8(B0a, A1a, acc[0][1], 0, 0, 0);
    acc[1][0] = __builtin_amdgcn_mfma_i32_32x32x32_i8(B1a, A0a, acc[1][0], 0, 0, 0);
    acc[1][1] = __builtin_amdgcn_mfma_i32_32x32x32_i8(B1a, A1a, acc[1][1], 0, 0, 0);
    acc[0][0] = __builtin_amdgcn_mfma_i32_32x32x32_i8(B0b, A0b, acc[0][0], 0, 0, 0);
    acc[0][1] = __builtin_amdgcn_mfma_i32_32x32x32_i8(B0b, A1b, acc[0][1], 0, 0, 0);
    acc[1][0] = __builtin_amdgcn_mfma_i32_32x32x32_i8(B1b, A0b, acc[1][0], 0, 0, 0);
    acc[1][1] = __builtin_amdgcn_mfma_i32_32x32x32_i8(B1b, A1b, acc[1][1], 0, 0, 0);
  }

  const float pact = scal[5];
  const int seqbase = rb * 256 + w64;
#pragma unroll
  for (int i = 0; i < 2; i++)
#pragma unroll
    for (int b = 0; b < 4; b++) {
      int colb = col0 + 32 * i + 8 * b + 4 * hi;
      float4 al = *(const float4*)(proj_alpha + colb);
      float4 bi = *(const float4*)(proj_bias + colb);
      const float* alp = (const float*)&al;
      const float* bip = (const float*)&bi;
#pragma unroll
      for (int j = 0; j < 2; j++) {
        int m = seqbase + 32 * j + l31;
        float4 o;
        float* op = (float*)&o;
#pragma unroll
        for (int c = 0; c < 4; c++)
          op[c] = fadd(fmul(fmul((float)acc[i][j][4 * b + c], alp[c]), pact),
                       bip[c]);
        *(float4*)(out + (size_t)m * CC + colb) = o;
      }
    }
}

extern "C" void kernel_launch(void* const* d_in, const int* in_sizes, int n_in,
                              void* d_out, int out_size, void* d_ws,
                              size_t ws_size, hipStream_t stream) {
  const float* x0 = (const float*)d_in[0];
  const float* qkv_w = (const float*)d_in[1];
  const float* qkv_alpha = (const float*)d_in[2];
  const float* qkv_bias = (const float*)d_in[3];
  const float* qkv_act_alpha = (const float*)d_in[4];
  const float* proj_w = (const float*)d_in[5];
  const float* proj_alpha = (const float*)d_in[6];
  const float* proj_bias = (const float*)d_in[7];
  const float* proj_act_alpha = (const float*)d_in[8];
  const float* normq_w = (const float*)d_in[9];
  const float* normq_b = (const float*)d_in[10];
  const float* normk_w = (const float*)d_in[11];
  const float* normk_b = (const float*)d_in[12];
  const float* qact_alpha = (const float*)d_in[13];
  const float* kact_alpha = (const float*)d_in[14];
  const float* vact_alpha = (const float*)d_in[15];
  const float* attnact_alpha = (const float*)d_in[16];

  char* ws = (char*)d_ws;
  size_t off = 0;
  auto alloc = [&](size_t bytes) -> char* {
    char* p = ws + off;
    off += (bytes + 255) & ~(size_t)255;
    return p;
  };
  float* scal = (float*)alloc(64 * 4);
  float* qparams = (float*)alloc(256 * 4);
  float* biasq = (float*)alloc(QKV_C * 4);
  int8_t* x0q = (int8_t*)alloc((size_t)M_ROWS * CC);   // tiled [12][16384][64]
  int8_t* wq = (int8_t*)alloc((size_t)QKV_C * CC);     // tiled [12][2304][64]
  int8_t* pwq = (int8_t*)alloc((size_t)CC * CC);       // tiled [12][768][64]
  int8_t* q2 = (int8_t*)alloc((size_t)BB * HH * NN * HD);
  int8_t* k2 = (int8_t*)alloc((size_t)BB * HH * NN * HD);
  int8_t* v2t = (int8_t*)alloc((size_t)BB * HH * NN * HD);
  int8_t* x1q = (int8_t*)alloc((size_t)M_ROWS * CC);

  prep_kernel<<<1, 256, 0, stream>>>(qkv_act_alpha, proj_act_alpha, qact_alpha,
                                     kact_alpha, vact_alpha, attnact_alpha,
                                     normq_w, normq_b, normk_w, normk_b,
                                     qkv_bias, qkv_alpha, scal, qparams, biasq);

  int total4 = M_ROWS * CC / 4;
  quant_x0_kernel<<<(total4 + 255) / 256, 256, 0, stream>>>(x0, scal, x0q,
                                                            total4);
  quant_w_kernel<<<(QKV_C * CC + 255) / 256, 256, 0, stream>>>(
      qkv_w, qkv_alpha, wq, QKV_C, QKV_C * CC);
  quant_w_kernel<<<(CC * CC + 255) / 256, 256, 0, stream>>>(
      proj_w, proj_alpha, pwq, CC, CC * CC);

  gemm_qkv_kernel<<<QKV_C / 64 * (M_ROWS / 256), 256, 0, stream>>>(
      x0q, wq, biasq, scal, qkv_alpha, qparams, q2, k2, v2t);

  attn_kernel<<<(NN / 64) * (BB * HH), 256, 0, stream>>>(q2, k2, v2t, scal,
                                                         x1q);

  gemm_proj_kernel<<<(CC / 64) * (M_ROWS / 256), 256, 0, stream>>>(
      x1q, pwq, proj_alpha, proj_bias, scal, (float*)d_out);
}